// Round 1
// baseline (5434.431 us; speedup 1.0000x reference)
//
#include <hip/hip_runtime.h>
#include <math.h>

// Problem constants
#define B_    2
#define S_    2048
#define HID_  2048
#define NH_   16
#define NKV_  8
#define D_    128
#define QR_   6
#define KR_   2
#define VR_   2
#define WIN_  1024
#define CAP_  50.0f
#define EPS_  1e-6f
// SCALE = D^-0.5
#define SCALE_ 0.08838834764831845f

// ---------------------------------------------------------------------------
// Generic fp32 GEMM: C[M,N] = A[M,K] @ W[K,N].  BM=BN=128, BK=16, 256 thr,
// 8x8 micro-tile (interleaved rows/cols: r = ty+16i, c = tx+16j).
// Assumes M%128==0, K%16==0 (true for all call sites). N arbitrary (guarded).
// ---------------------------------------------------------------------------
__global__ __launch_bounds__(256) void gemm_f32(const float* __restrict__ A,
                                                const float* __restrict__ Bw,
                                                float* __restrict__ C,
                                                int M, int N, int K) {
    __shared__ float As[16][132];   // As[kk][row], pad to 132 (16B-aligned rows)
    __shared__ float Bs[16][132];   // Bs[kk][col]

    const int col0 = blockIdx.x * 128;
    const int row0 = blockIdx.y * 128;
    const int t  = threadIdx.x;
    const int tx = t & 15;
    const int ty = t >> 4;
    const bool fullN = (col0 + 128 <= N);

    float acc[8][8];
#pragma unroll
    for (int i = 0; i < 8; ++i)
#pragma unroll
        for (int j = 0; j < 8; ++j) acc[i][j] = 0.f;

    for (int k0 = 0; k0 < K; k0 += 16) {
        // A tile 128x16 -> As transposed. 512 float4 loads, 2 per thread.
#pragma unroll
        for (int u = 0; u < 2; ++u) {
            int f  = t + u * 256;
            int r  = f >> 2;
            int c4 = (f & 3) * 4;
            const float4 v = *(const float4*)&A[(size_t)(row0 + r) * K + k0 + c4];
            As[c4 + 0][r] = v.x; As[c4 + 1][r] = v.y;
            As[c4 + 2][r] = v.z; As[c4 + 3][r] = v.w;
        }
        // B tile 16x128 -> Bs. 512 float4 loads, 2 per thread.
#pragma unroll
        for (int u = 0; u < 2; ++u) {
            int f  = t + u * 256;
            int r  = f >> 5;
            int c4 = (f & 31) * 4;
            float4 v;
            if (fullN) {
                v = *(const float4*)&Bw[(size_t)(k0 + r) * N + col0 + c4];
            } else {
                const size_t base = (size_t)(k0 + r) * N;
                v.x = (col0 + c4 + 0 < N) ? Bw[base + col0 + c4 + 0] : 0.f;
                v.y = (col0 + c4 + 1 < N) ? Bw[base + col0 + c4 + 1] : 0.f;
                v.z = (col0 + c4 + 2 < N) ? Bw[base + col0 + c4 + 2] : 0.f;
                v.w = (col0 + c4 + 3 < N) ? Bw[base + col0 + c4 + 3] : 0.f;
            }
            *(float4*)&Bs[r][c4] = v;
        }
        __syncthreads();
#pragma unroll
        for (int kk = 0; kk < 16; ++kk) {
            float a[8], b[8];
#pragma unroll
            for (int i = 0; i < 8; ++i) a[i] = As[kk][ty + 16 * i];
#pragma unroll
            for (int j = 0; j < 8; ++j) b[j] = Bs[kk][tx + 16 * j];
#pragma unroll
            for (int i = 0; i < 8; ++i)
#pragma unroll
                for (int j = 0; j < 8; ++j)
                    acc[i][j] = fmaf(a[i], b[j], acc[i][j]);
        }
        __syncthreads();
    }
#pragma unroll
    for (int i = 0; i < 8; ++i) {
        const int r = row0 + ty + 16 * i;
#pragma unroll
        for (int j = 0; j < 8; ++j) {
            const int c = col0 + tx + 16 * j;
            if (c < N) C[(size_t)r * N + c] = acc[i][j];
        }
    }
}

// ---------------------------------------------------------------------------
// RMSNorm (+1+w gain) + RoPE over one D=128 vector per block (64 threads).
// X layout: [(b*S+s)*R + r][D].  cos/sin: [S][64].
// ---------------------------------------------------------------------------
__global__ __launch_bounds__(64) void norm_rope_kernel(float* __restrict__ X,
                                                       const float* __restrict__ w,
                                                       const float* __restrict__ cosT,
                                                       const float* __restrict__ sinT,
                                                       int R) {
    const int blk = blockIdx.x;
    const int s   = (blk / R) % S_;
    const int l   = threadIdx.x;
    float* v = X + (size_t)blk * D_;
    float x1 = v[l];
    float x2 = v[l + 64];
    float ss = x1 * x1 + x2 * x2;
#pragma unroll
    for (int off = 32; off; off >>= 1) ss += __shfl_xor(ss, off);
    const float inv = 1.0f / sqrtf(ss * (1.0f / 128.0f) + EPS_);
    x1 *= inv * (1.0f + w[l]);
    x2 *= inv * (1.0f + w[l + 64]);
    const float c  = cosT[s * 64 + l];
    const float sn = sinT[s * 64 + l];
    v[l]      = x1 * c - x2 * sn;
    v[l + 64] = x1 * sn + x2 * c;
}

// ---------------------------------------------------------------------------
// Scatter projected K/V factors into effective caches at kv_write_indices.
// One block per (b,s), 256 threads.
// ---------------------------------------------------------------------------
__global__ __launch_bounds__(256) void scatter_kernel(const float* __restrict__ pAk,
                                                      const float* __restrict__ pBk,
                                                      const float* __restrict__ pAv,
                                                      const float* __restrict__ pBv,
                                                      const int* __restrict__ idx,
                                                      float* __restrict__ eKA,
                                                      float* __restrict__ eKB,
                                                      float* __restrict__ eVA,
                                                      float* __restrict__ eVB) {
    const int bs = blockIdx.x;
    const int b  = bs / S_;
    const int s  = bs % S_;
    const int di = idx[s];
    const size_t src = (size_t)bs;
    const size_t dst = (size_t)b * S_ + di;
    const int t = threadIdx.x;
    if (t < NKV_ * KR_) eKA[dst * (NKV_ * KR_) + t] = pAk[src * (NKV_ * KR_) + t];
    if (t < NKV_ * VR_) eVA[dst * (NKV_ * VR_) + t] = pAv[src * (NKV_ * VR_) + t];
    eKB[dst * (KR_ * D_) + t] = pBk[src * (KR_ * D_) + t];
    eVB[dst * (VR_ * D_) + t] = pBv[src * (VR_ * D_) + t];
}

// ---------------------------------------------------------------------------
// Assemble Q (b,h,s,d), K (b,kv,s,d), V (b,kv,s,d) from rank factors.
// One block per (b,s), 256 threads.
// ---------------------------------------------------------------------------
__global__ __launch_bounds__(256) void assemble_kernel(const float* __restrict__ pAq,
                                                       const float* __restrict__ pBq,
                                                       const float* __restrict__ eKA,
                                                       const float* __restrict__ eKB,
                                                       const float* __restrict__ eVA,
                                                       const float* __restrict__ eVB,
                                                       float* __restrict__ Qo,
                                                       float* __restrict__ Ko,
                                                       float* __restrict__ Vo) {
    __shared__ float aq[NH_ * QR_];   // 96
    __shared__ float bq[QR_ * D_];    // 768
    __shared__ float ka[NKV_ * KR_];  // 16
    __shared__ float kb[KR_ * D_];    // 256
    __shared__ float va[NKV_ * VR_];  // 16
    __shared__ float vb[VR_ * D_];    // 256

    const int bs = blockIdx.x;
    const int b  = bs / S_;
    const int s  = bs % S_;
    const int t  = threadIdx.x;

    if (t < 96) aq[t] = pAq[(size_t)bs * 96 + t];
    for (int i = t; i < 768; i += 256) bq[i] = pBq[(size_t)bs * 768 + i];
    if (t < 16) { ka[t] = eKA[(size_t)bs * 16 + t]; va[t] = eVA[(size_t)bs * 16 + t]; }
    kb[t] = eKB[(size_t)bs * 256 + t];
    vb[t] = eVB[(size_t)bs * 256 + t];
    __syncthreads();

    const float qf = SCALE_ / (float)QR_;
#pragma unroll
    for (int i = 0; i < 8; ++i) {      // Q: NH*D = 2048 outputs
        const int o = t + 256 * i;
        const int h = o >> 7, d = o & 127;
        float acc = 0.f;
#pragma unroll
        for (int r = 0; r < QR_; ++r) acc = fmaf(aq[h * QR_ + r], bq[r * D_ + d], acc);
        Qo[(((size_t)b * NH_ + h) * S_ + s) * D_ + d] = acc * qf;
    }
#pragma unroll
    for (int i = 0; i < 4; ++i) {      // K,V: NKV*D = 1024 outputs each
        const int o = t + 256 * i;
        const int g = o >> 7, d = o & 127;
        const float kk = 0.5f * (ka[g * 2 + 0] * kb[d] + ka[g * 2 + 1] * kb[D_ + d]);
        const float vv = 0.5f * (va[g * 2 + 0] * vb[d] + va[g * 2 + 1] * vb[D_ + d]);
        Ko[(((size_t)b * NKV_ + g) * S_ + s) * D_ + d] = kk;
        Vo[(((size_t)b * NKV_ + g) * S_ + s) * D_ + d] = vv;
    }
}

// ---------------------------------------------------------------------------
// Windowed causal attention with tanh soft-cap, flash-style online softmax.
// Grid (S/64, NH, B), 256 threads. 64x64 tiles, fp32. LDS ~116 KB (1 blk/CU).
// Score phase: thread -> (qi = t>>2, 16 keys). PV phase: thread -> (row=t>>2,
// d-slice d = (t&3) + 4*dd) so Vs reads hit 4 distinct banks.
// ---------------------------------------------------------------------------
__global__ __launch_bounds__(256) void attn_kernel(const float* __restrict__ Q,
                                                   const float* __restrict__ K,
                                                   const float* __restrict__ V,
                                                   float* __restrict__ O) {
    __shared__ float Qs[64][129];
    __shared__ float Ks[64][129];
    __shared__ float Vs[64][129];
    __shared__ float Ss[64][65];
    __shared__ float corrs[64];
    __shared__ float invl[64];

    const int qt = blockIdx.x, h = blockIdx.y, b = blockIdx.z;
    const int kv = h / (NH_ / NKV_);
    const int q0 = qt * 64;
    const int t  = threadIdx.x;

    const float* Qb = Q + ((size_t)b * NH_  + h)  * S_ * D_;
    const float* Kb = K + ((size_t)b * NKV_ + kv) * S_ * D_;
    const float* Vb = V + ((size_t)b * NKV_ + kv) * S_ * D_;

    // load Q tile (64x128)
    for (int f = t; f < 2048; f += 256) {
        const int r = f >> 5, c4 = (f & 31) * 4;
        const float4 v = *(const float4*)&Qb[(size_t)(q0 + r) * D_ + c4];
        Qs[r][c4 + 0] = v.x; Qs[r][c4 + 1] = v.y;
        Qs[r][c4 + 2] = v.z; Qs[r][c4 + 3] = v.w;
    }

    const int orow = t >> 2, odg = t & 3;
    float oacc[32];
#pragma unroll
    for (int i = 0; i < 32; ++i) oacc[i] = 0.f;
    float m_run = -INFINITY, l_run = 0.f;   // valid in threads t<64 (row t)

    const int kstart  = (q0 - (WIN_ - 1)) > 0 ? (q0 - (WIN_ - 1)) : 0;
    const int k_begin = kstart & ~63;
    const int k_end   = q0 + 64;            // exclusive; <= S_ always

    for (int k0 = k_begin; k0 < k_end; k0 += 64) {
        // load K,V tiles
        for (int f = t; f < 2048; f += 256) {
            const int r = f >> 5, c4 = (f & 31) * 4;
            const float4 kvv = *(const float4*)&Kb[(size_t)(k0 + r) * D_ + c4];
            const float4 vvv = *(const float4*)&Vb[(size_t)(k0 + r) * D_ + c4];
            Ks[r][c4 + 0] = kvv.x; Ks[r][c4 + 1] = kvv.y;
            Ks[r][c4 + 2] = kvv.z; Ks[r][c4 + 3] = kvv.w;
            Vs[r][c4 + 0] = vvv.x; Vs[r][c4 + 1] = vvv.y;
            Vs[r][c4 + 2] = vvv.z; Vs[r][c4 + 3] = vvv.w;
        }
        __syncthreads();

        // scores: each thread computes 16 of 64x64
        {
            const int qi = t >> 2;
            const int kb = (t & 3) * 16;
            float sc[16];
#pragma unroll
            for (int j = 0; j < 16; ++j) sc[j] = 0.f;
            for (int d = 0; d < D_; ++d) {
                const float qv = Qs[qi][d];
#pragma unroll
                for (int j = 0; j < 16; ++j)
                    sc[j] = fmaf(qv, Ks[kb + j][d], sc[j]);
            }
            const int gi = q0 + qi;
#pragma unroll
            for (int j = 0; j < 16; ++j) {
                const int gj = k0 + kb + j;
                const float sv = tanhf(sc[j] * (1.0f / CAP_)) * CAP_;
                const bool ok = (gj <= gi) && (gj > gi - WIN_);
                Ss[qi][kb + j] = ok ? sv : -INFINITY;
            }
        }
        __syncthreads();

        // online softmax per row (threads 0..63)
        if (t < 64) {
            float tm = -INFINITY;
            for (int j = 0; j < 64; ++j) tm = fmaxf(tm, Ss[t][j]);
            const float mnew = fmaxf(m_run, tm);
            float corr;
            if (mnew == -INFINITY) {            // whole row masked so far
                corr = 1.0f;
                for (int j = 0; j < 64; ++j) Ss[t][j] = 0.f;
            } else {
                corr = expf(m_run - mnew);      // m_run==-inf -> 0
                float lsum = 0.f;
                for (int j = 0; j < 64; ++j) {
                    const float p = expf(Ss[t][j] - mnew);  // -inf -> 0
                    Ss[t][j] = p;
                    lsum += p;
                }
                l_run = l_run * corr + lsum;
                m_run = mnew;
            }
            corrs[t] = corr;
        }
        __syncthreads();

        // PV: O[row][d] = O*corr + sum_kj P[row][kj] * V[kj][d]
        {
            const float corr = corrs[orow];
#pragma unroll
            for (int i = 0; i < 32; ++i) oacc[i] *= corr;
            for (int kj = 0; kj < 64; ++kj) {
                const float p = Ss[orow][kj];
#pragma unroll
                for (int i = 0; i < 32; ++i)
                    oacc[i] = fmaf(p, Vs[kj][odg + 4 * i], oacc[i]);
            }
        }
        __syncthreads();   // protect Ks/Vs/Ss before next tile's loads
    }

    if (t < 64) invl[t] = (l_run > 0.f) ? 1.0f / l_run : 0.f;
    __syncthreads();
    const float il = invl[orow];
    float* op = O + ((size_t)(b * S_ + q0 + orow)) * (NH_ * D_) + h * D_;
#pragma unroll
    for (int i = 0; i < 32; ++i) op[odg + 4 * i] = oacc[i] * il;
}

// ---------------------------------------------------------------------------
// Launch
// ---------------------------------------------------------------------------
extern "C" void kernel_launch(void* const* d_in, const int* in_sizes, int n_in,
                              void* d_out, int out_size, void* d_ws, size_t ws_size,
                              hipStream_t stream) {
    const float* hs   = (const float*)d_in[0];
    const float* cosT = (const float*)d_in[1];
    const float* sinT = (const float*)d_in[2];
    const float* WAq  = (const float*)d_in[3];
    const float* WAk  = (const float*)d_in[4];
    const float* WAv  = (const float*)d_in[5];
    const float* WBq  = (const float*)d_in[6];
    const float* WBk  = (const float*)d_in[7];
    const float* WBv  = (const float*)d_in[8];
    const float* Wo   = (const float*)d_in[9];
    const float* qnw  = (const float*)d_in[10];
    const float* knw  = (const float*)d_in[11];
    const float* kcA  = (const float*)d_in[12];
    const float* kcB  = (const float*)d_in[13];
    const float* vcA  = (const float*)d_in[14];
    const float* vcB  = (const float*)d_in[15];
    const int*   kidx = (const int*)d_in[16];
    float* out = (float*)d_out;

    const size_t MROW = (size_t)B_ * S_;     // 4096
    float* p = (float*)d_ws;
    float* pAq = p;                 p += MROW * (NH_ * QR_);    // 96
    float* pAk = p;                 p += MROW * (NKV_ * KR_);   // 16
    float* pAv = p;                 p += MROW * (NKV_ * VR_);   // 16
    float* pBq = p;                 p += MROW * (QR_ * D_);     // 768
    float* pBk = p;                 p += MROW * (KR_ * D_);     // 256
    float* pBv = p;                 p += MROW * (VR_ * D_);     // 256
    float* eKA = p;                 p += MROW * (NKV_ * KR_);
    float* eKB = p;                 p += MROW * (KR_ * D_);
    float* eVA = p;                 p += MROW * (NKV_ * VR_);
    float* eVB = p;                 p += MROW * (VR_ * D_);
    float* Qb  = p;                 p += (size_t)B_ * NH_  * S_ * D_;
    float* Kb  = p;                 p += (size_t)B_ * NKV_ * S_ * D_;
    float* Vb  = p;                 p += (size_t)B_ * NKV_ * S_ * D_;
    float* aO  = p;                 p += MROW * (NH_ * D_);

    const int M = (int)MROW;   // 4096
    // projections
    gemm_f32<<<dim3(1,  M / 128), 256, 0, stream>>>(hs, WAq, pAq, M,  96, HID_);
    gemm_f32<<<dim3(1,  M / 128), 256, 0, stream>>>(hs, WAk, pAk, M,  16, HID_);
    gemm_f32<<<dim3(1,  M / 128), 256, 0, stream>>>(hs, WAv, pAv, M,  16, HID_);
    gemm_f32<<<dim3(6,  M / 128), 256, 0, stream>>>(hs, WBq, pBq, M, 768, HID_);
    gemm_f32<<<dim3(2,  M / 128), 256, 0, stream>>>(hs, WBk, pBk, M, 256, HID_);
    gemm_f32<<<dim3(2,  M / 128), 256, 0, stream>>>(hs, WBv, pBv, M, 256, HID_);

    // rmsnorm + rope on B_q, B_k
    norm_rope_kernel<<<B_ * S_ * QR_, 64, 0, stream>>>(pBq, qnw, cosT, sinT, QR_);
    norm_rope_kernel<<<B_ * S_ * KR_, 64, 0, stream>>>(pBk, knw, cosT, sinT, KR_);

    // effective caches = input caches scatter-updated at kv_write_indices
    hipMemcpyAsync(eKA, kcA, MROW * (NKV_ * KR_) * sizeof(float), hipMemcpyDeviceToDevice, stream);
    hipMemcpyAsync(eKB, kcB, MROW * (KR_  * D_)  * sizeof(float), hipMemcpyDeviceToDevice, stream);
    hipMemcpyAsync(eVA, vcA, MROW * (NKV_ * VR_) * sizeof(float), hipMemcpyDeviceToDevice, stream);
    hipMemcpyAsync(eVB, vcB, MROW * (VR_  * D_)  * sizeof(float), hipMemcpyDeviceToDevice, stream);
    scatter_kernel<<<B_ * S_, 256, 0, stream>>>(pAk, pBk, pAv, pBv, kidx, eKA, eKB, eVA, eVB);

    // assemble Q/K/V
    assemble_kernel<<<B_ * S_, 256, 0, stream>>>(pAq, pBq, eKA, eKB, eVA, eVB, Qb, Kb, Vb);

    // attention
    attn_kernel<<<dim3(S_ / 64, NH_, B_), 256, 0, stream>>>(Qb, Kb, Vb, aO);

    // output projection -> d_out
    gemm_f32<<<dim3(HID_ / 128, M / 128), 256, 0, stream>>>(aO, Wo, out, M, HID_, HID_);
}

// Round 2
// 1810.158 us; speedup vs baseline: 3.0022x; 3.0022x over previous
//
#include <hip/hip_runtime.h>
#include <math.h>

#define B_    2
#define S_    2048
#define HID_  2048
#define NH_   16
#define NKV_  8
#define D_    128
#define QR_   6
#define KR_   2
#define VR_   2
#define WIN_  1024
#define CAP_  50.0f
#define EPS_  1e-6f
#define SCALE_ 0.08838834764831845f

// packed projection column offsets in Cp[4096][1408]
#define OFF_AQ 0
#define OFF_AK 96
#define OFF_AV 112
#define OFF_BQ 128
#define OFF_BK 896
#define OFF_BV 1152
#define NPACK  1408

using short8 = __attribute__((ext_vector_type(8))) short;
using f32x4  = __attribute__((ext_vector_type(4))) float;
using u16x4  = __attribute__((ext_vector_type(4))) unsigned short;

__device__ __forceinline__ unsigned short f2bf(float f) {
    union { float f; unsigned u; } v; v.f = f;
    unsigned r = v.u + 0x7FFFu + ((v.u >> 16) & 1u);   // RNE
    return (unsigned short)(r >> 16);
}

// ---------------------------------------------------------------------------
// fp32 -> bf16 elementwise (vectorized), n4 = count/4
// ---------------------------------------------------------------------------
__global__ __launch_bounds__(256) void cvt_f32_bf16(const float* __restrict__ src,
                                                    unsigned short* __restrict__ dst,
                                                    int n4) {
    int i = blockIdx.x * 256 + threadIdx.x;
    if (i < n4) {
        float4 v = ((const float4*)src)[i];
        u16x4 o;
        o[0] = f2bf(v.x); o[1] = f2bf(v.y); o[2] = f2bf(v.z); o[3] = f2bf(v.w);
        ((u16x4*)dst)[i] = o;
    }
}

// ---------------------------------------------------------------------------
// Transpose-pack: dst[(rowOff+n)*dstStride + k] = bf16(src[k*N + n])
// grid (ceil(N/32), K/32), 256 thr (32x8).
// ---------------------------------------------------------------------------
__global__ __launch_bounds__(256) void transpose_pack(const float* __restrict__ src,
                                                      int K, int N,
                                                      unsigned short* __restrict__ dst,
                                                      int rowOff, int dstStride) {
    __shared__ float tile[32][33];
    const int k0 = blockIdx.y * 32, n0 = blockIdx.x * 32;
    const int tx = threadIdx.x & 31, ty = threadIdx.x >> 5;
#pragma unroll
    for (int i = ty; i < 32; i += 8) {
        const int k = k0 + i, n = n0 + tx;
        tile[i][tx] = (n < N) ? src[(size_t)k * N + n] : 0.f;
    }
    __syncthreads();
#pragma unroll
    for (int i = ty; i < 32; i += 8) {
        const int n = n0 + i, k = k0 + tx;
        if (n < N) dst[(size_t)(rowOff + n) * dstStride + k] = f2bf(tile[tx][i]);
    }
}

// ---------------------------------------------------------------------------
// bf16 MFMA GEMM: C[M,N] f32 = A[M,K] @ Bt[N,K]^T, bf16 inputs.
// 128x128 tile, BK=32, 256 thr (4 waves, 2x2 of 64x64), 16x16x32 MFMA.
// Reg-staged LDS with XOR-16B swizzle: elem (r, kg of 8) at byte
// r*64 + ((kg ^ ((r>>1)&3))*16). M%128==0, N%128==0, K%32==0.
// ---------------------------------------------------------------------------
__global__ __launch_bounds__(256) void gemm_bf16(const unsigned short* __restrict__ A,
                                                 const unsigned short* __restrict__ Bt,
                                                 float* __restrict__ C,
                                                 int M, int N, int K) {
    __shared__ unsigned short As[4096];   // 128 x 32, swizzled, 8 KB
    __shared__ unsigned short Bs[4096];

    const int t    = threadIdx.x;
    const int lane = t & 63, wid = t >> 6;
    const int wr = wid >> 1, wc = wid & 1;
    const int row0 = blockIdx.y * 128, col0 = blockIdx.x * 128;

    // staging slots: slot s -> r=s>>2, g=s&3; LDS write linear at s*16B,
    // global source column-group cg = g ^ ((r>>1)&3)  (pre-swizzled source)
    const int s0 = t, s1 = t + 256;
    const int r0 = s0 >> 2, cg0 = (s0 & 3) ^ ((r0 >> 1) & 3);
    const int r1 = s1 >> 2, cg1 = (s1 & 3) ^ ((r1 >> 1) & 3);
    const size_t aOff0 = (size_t)(row0 + r0) * K + cg0 * 8;
    const size_t aOff1 = (size_t)(row0 + r1) * K + cg1 * 8;
    const size_t bOff0 = (size_t)(col0 + r0) * K + cg0 * 8;
    const size_t bOff1 = (size_t)(col0 + r1) * K + cg1 * 8;

    f32x4 acc[4][4];
#pragma unroll
    for (int m = 0; m < 4; ++m)
#pragma unroll
        for (int n = 0; n < 4; ++n) { acc[m][n][0]=0.f; acc[m][n][1]=0.f; acc[m][n][2]=0.f; acc[m][n][3]=0.f; }

    // fragment LDS offsets (ushort units), per m/n
    const int l15 = lane & 15, kg = lane >> 4;
    const int rsw = ((l15 >> 1) & 3);           // (row>>1)&3 — m*16, w*64 are 0 mod 4 after >>1&3
    int aoff[4], boff[4];
#pragma unroll
    for (int m = 0; m < 4; ++m) {
        const int ra = wr * 64 + m * 16 + l15;
        aoff[m] = ra * 32 + ((kg ^ rsw) * 8);
        const int rb = wc * 64 + m * 16 + l15;
        boff[m] = rb * 32 + ((kg ^ rsw) * 8);
    }

    for (int k0 = 0; k0 < K; k0 += 32) {
        const short8 av0 = *(const short8*)(A  + aOff0 + k0);
        const short8 av1 = *(const short8*)(A  + aOff1 + k0);
        const short8 bv0 = *(const short8*)(Bt + bOff0 + k0);
        const short8 bv1 = *(const short8*)(Bt + bOff1 + k0);
        __syncthreads();                         // previous iter's reads done
        *(short8*)(As + s0 * 8) = av0;
        *(short8*)(As + s1 * 8) = av1;
        *(short8*)(Bs + s0 * 8) = bv0;
        *(short8*)(Bs + s1 * 8) = bv1;
        __syncthreads();
        short8 a[4], b[4];
#pragma unroll
        for (int m = 0; m < 4; ++m) a[m] = *(const short8*)(As + aoff[m]);
#pragma unroll
        for (int n = 0; n < 4; ++n) b[n] = *(const short8*)(Bs + boff[n]);
#pragma unroll
        for (int m = 0; m < 4; ++m)
#pragma unroll
            for (int n = 0; n < 4; ++n)
                acc[m][n] = __builtin_amdgcn_mfma_f32_16x16x32_bf16(a[m], b[n], acc[m][n], 0, 0, 0);
    }

    // epilogue: D row = (lane>>4)*4 + q, col = lane&15 (measured layout)
#pragma unroll
    for (int m = 0; m < 4; ++m) {
#pragma unroll
        for (int n = 0; n < 4; ++n) {
            const int cc = col0 + wc * 64 + n * 16 + l15;
#pragma unroll
            for (int q = 0; q < 4; ++q) {
                const int rr = row0 + wr * 64 + m * 16 + kg * 4 + q;
                C[(size_t)rr * N + cc] = acc[m][n][q];
            }
        }
    }
}

// ---------------------------------------------------------------------------
// RMSNorm + RoPE in-place on packed Cp columns. One (bs, r) per 64-thr block.
// ---------------------------------------------------------------------------
__global__ __launch_bounds__(64) void norm_rope(float* __restrict__ Cp,
                                                int colOff, int R,
                                                const float* __restrict__ w,
                                                const float* __restrict__ cosT,
                                                const float* __restrict__ sinT) {
    const int blk = blockIdx.x;
    const int bs = blk / R, r = blk % R;
    const int s = bs % S_;
    const int l = threadIdx.x;
    float* v = Cp + (size_t)bs * NPACK + colOff + r * D_;
    float x1 = v[l];
    float x2 = v[l + 64];
    float ss = x1 * x1 + x2 * x2;
#pragma unroll
    for (int off = 32; off; off >>= 1) ss += __shfl_xor(ss, off);
    const float inv = 1.0f / sqrtf(ss * (1.0f / 128.0f) + EPS_);
    x1 *= inv * (1.0f + w[l]);
    x2 *= inv * (1.0f + w[l + 64]);
    const float c  = cosT[s * 64 + l];
    const float sn = sinT[s * 64 + l];
    v[l]      = x1 * c - x2 * sn;
    v[l + 64] = x1 * sn + x2 * c;
}

// ---------------------------------------------------------------------------
// Scatter packed K/V factors into effective caches at kv_write_indices.
// ---------------------------------------------------------------------------
__global__ __launch_bounds__(256) void scatter_kernel(const float* __restrict__ Cp,
                                                      const int* __restrict__ idx,
                                                      float* __restrict__ eKA,
                                                      float* __restrict__ eKB,
                                                      float* __restrict__ eVA,
                                                      float* __restrict__ eVB) {
    const int bs = blockIdx.x;
    const int b  = bs / S_;
    const int s  = bs % S_;
    const int di = idx[s];
    const size_t dst = (size_t)b * S_ + di;
    const int t = threadIdx.x;
    const float* rowp = Cp + (size_t)bs * NPACK;
    if (t < 16) { eKA[dst * 16 + t] = rowp[OFF_AK + t]; eVA[dst * 16 + t] = rowp[OFF_AV + t]; }
    eKB[dst * 256 + t] = rowp[OFF_BK + t];
    eVB[dst * 256 + t] = rowp[OFF_BV + t];
}

// ---------------------------------------------------------------------------
// Assemble Q (b,h,s,d) [scaled], K,V (b,kv,s,d) from rank factors. fp32.
// ---------------------------------------------------------------------------
__global__ __launch_bounds__(256) void assemble_kernel(const float* __restrict__ Cp,
                                                       const float* __restrict__ eKA,
                                                       const float* __restrict__ eKB,
                                                       const float* __restrict__ eVA,
                                                       const float* __restrict__ eVB,
                                                       float* __restrict__ Qo,
                                                       float* __restrict__ Ko,
                                                       float* __restrict__ Vo) {
    __shared__ float aq[96];
    __shared__ float bq[768];
    __shared__ float ka[16];
    __shared__ float kb[256];
    __shared__ float va[16];
    __shared__ float vb[256];

    const int bs = blockIdx.x;
    const int b  = bs / S_;
    const int s  = bs % S_;
    const int t  = threadIdx.x;
    const float* rowp = Cp + (size_t)bs * NPACK;

    if (t < 96) aq[t] = rowp[OFF_AQ + t];
    for (int i = t; i < 768; i += 256) bq[i] = rowp[OFF_BQ + i];
    if (t < 16) { ka[t] = eKA[(size_t)bs * 16 + t]; va[t] = eVA[(size_t)bs * 16 + t]; }
    kb[t] = eKB[(size_t)bs * 256 + t];
    vb[t] = eVB[(size_t)bs * 256 + t];
    __syncthreads();

    const float qf = SCALE_ / (float)QR_;
#pragma unroll
    for (int i = 0; i < 8; ++i) {
        const int o = t + 256 * i;
        const int h = o >> 7, d = o & 127;
        float acc = 0.f;
#pragma unroll
        for (int r = 0; r < QR_; ++r) acc = fmaf(aq[h * QR_ + r], bq[r * D_ + d], acc);
        Qo[(((size_t)b * NH_ + h) * S_ + s) * D_ + d] = acc * qf;
    }
#pragma unroll
    for (int i = 0; i < 4; ++i) {
        const int o = t + 256 * i;
        const int g = o >> 7, d = o & 127;
        const float kk = 0.5f * (ka[g * 2 + 0] * kb[d] + ka[g * 2 + 1] * kb[D_ + d]);
        const float vv = 0.5f * (va[g * 2 + 0] * vb[d] + va[g * 2 + 1] * vb[D_ + d]);
        Ko[(((size_t)b * NKV_ + g) * S_ + s) * D_ + d] = kk;
        Vo[(((size_t)b * NKV_ + g) * S_ + s) * D_ + d] = vv;
    }
}

// ---------------------------------------------------------------------------
// Windowed causal attention, tanh soft-cap, flash online softmax. fp32.
// 64 q-rows/block, 256 thr. Thread (qi=t>>2, kb=t&3): 16 keys (kb+4j) in the
// score phase; softmax fused in-register via 4-lane shfl reduce; PV covers
// d = kb*16 + (u&3)*4 + (u>>2)*64. Output written as bf16 (feeds out-proj).
// All hot LDS patterns <=2-way or 4-quad-broadcast (conflict-free).
// ---------------------------------------------------------------------------
__global__ __launch_bounds__(256) void attn_kernel(const float* __restrict__ Q,
                                                   const float* __restrict__ K,
                                                   const float* __restrict__ V,
                                                   unsigned short* __restrict__ O) {
    __shared__ float Qs[64][132];
    __shared__ float Ks[64][132];
    __shared__ float Vs[64][132];
    __shared__ float Ss[64][68];

    const int qt = blockIdx.x, h = blockIdx.y, b = blockIdx.z;
    const int kv = h / (NH_ / NKV_);
    const int q0 = qt * 64;
    const int t  = threadIdx.x;
    const int qi = t >> 2, kb = t & 3;

    const float* Qb = Q + ((size_t)b * NH_  + h)  * S_ * D_;
    const float* Kb = K + ((size_t)b * NKV_ + kv) * S_ * D_;
    const float* Vb = V + ((size_t)b * NKV_ + kv) * S_ * D_;

    // load Q tile (float4, conflict-free: 8 lanes per bank-quad)
    for (int f = t; f < 2048; f += 256) {
        const int r = f >> 5, c4 = (f & 31) * 4;
        *(float4*)&Qs[r][c4] = *(const float4*)&Qb[(size_t)(q0 + r) * D_ + c4];
    }

    float4 o4[8];
#pragma unroll
    for (int u = 0; u < 8; ++u) { o4[u].x = 0.f; o4[u].y = 0.f; o4[u].z = 0.f; o4[u].w = 0.f; }
    float m_run = -INFINITY, l_run = 0.f;
    const int gi = q0 + qi;

    const int kstart  = (q0 - (WIN_ - 1)) > 0 ? (q0 - (WIN_ - 1)) : 0;
    const int k_begin = kstart & ~63;
    const int k_end   = q0 + 64;

    for (int k0 = k_begin; k0 < k_end; k0 += 64) {
        for (int f = t; f < 2048; f += 256) {
            const int r = f >> 5, c4 = (f & 31) * 4;
            *(float4*)&Ks[r][c4] = *(const float4*)&Kb[(size_t)(k0 + r) * D_ + c4];
            *(float4*)&Vs[r][c4] = *(const float4*)&Vb[(size_t)(k0 + r) * D_ + c4];
        }
        __syncthreads();

        // ---- scores for 16 keys: kj = kb + 4j ----
        float sc[16];
#pragma unroll
        for (int j = 0; j < 16; ++j) sc[j] = 0.f;
        for (int d0 = 0; d0 < D_; d0 += 4) {
            const float4 q4 = *(const float4*)&Qs[qi][d0];
#pragma unroll
            for (int j = 0; j < 16; ++j) {
                const float4 k4 = *(const float4*)&Ks[kb + 4 * j][d0];
                sc[j] = fmaf(q4.x, k4.x, fmaf(q4.y, k4.y, fmaf(q4.z, k4.z, fmaf(q4.w, k4.w, sc[j]))));
            }
        }

        // ---- tanh cap + mask + in-register online softmax ----
        float tm = -INFINITY;
#pragma unroll
        for (int j = 0; j < 16; ++j) {
            const float e  = __expf(sc[j] * (2.0f / CAP_));     // e^{2x/cap}
            const float sv = CAP_ - (2.0f * CAP_) / (e + 1.0f); // cap*tanh(x/cap)
            const int gj = k0 + kb + 4 * j;
            const bool ok = (gj <= gi) && (gj > gi - WIN_);
            sc[j] = ok ? sv : -INFINITY;
            tm = fmaxf(tm, sc[j]);
        }
        tm = fmaxf(tm, __shfl_xor(tm, 1));
        tm = fmaxf(tm, __shfl_xor(tm, 2));
        const float mnew  = fmaxf(m_run, tm);
        const float msafe = (mnew > -INFINITY) ? mnew : 0.f;
        const float corr  = __expf(m_run - msafe);              // -inf -> 0
        float lsum = 0.f;
#pragma unroll
        for (int j = 0; j < 16; ++j) {
            const float p = __expf(sc[j] - msafe);              // masked -> 0
            lsum += p;
            Ss[qi][kb + 4 * j] = p;
        }
        lsum += __shfl_xor(lsum, 1);
        lsum += __shfl_xor(lsum, 2);
        l_run = l_run * corr + lsum;
        m_run = mnew;
        __syncthreads();   // Ss visible (also keeps waves phase-locked)

        // ---- PV ----
#pragma unroll
        for (int u = 0; u < 8; ++u) { o4[u].x *= corr; o4[u].y *= corr; o4[u].z *= corr; o4[u].w *= corr; }
        for (int kj = 0; kj < 64; ++kj) {
            const float p = Ss[qi][kj];
#pragma unroll
            for (int u = 0; u < 8; ++u) {
                const int d0 = kb * 16 + (u & 3) * 4 + (u >> 2) * 64;
                const float4 vv = *(const float4*)&Vs[kj][d0];
                o4[u].x = fmaf(p, vv.x, o4[u].x);
                o4[u].y = fmaf(p, vv.y, o4[u].y);
                o4[u].z = fmaf(p, vv.z, o4[u].z);
                o4[u].w = fmaf(p, vv.w, o4[u].w);
            }
        }
        __syncthreads();   // protect Ks/Vs/Ss before next tile's staging
    }

    const float il = (l_run > 0.f) ? 1.0f / l_run : 0.f;
    unsigned short* op = O + ((size_t)(b * S_ + q0 + qi)) * (NH_ * D_) + h * D_;
#pragma unroll
    for (int u = 0; u < 8; ++u) {
        const int d0 = kb * 16 + (u & 3) * 4 + (u >> 2) * 64;
        u16x4 pk;
        pk[0] = f2bf(o4[u].x * il);
        pk[1] = f2bf(o4[u].y * il);
        pk[2] = f2bf(o4[u].z * il);
        pk[3] = f2bf(o4[u].w * il);
        *(u16x4*)&op[d0] = pk;
    }
}

// ---------------------------------------------------------------------------
// Launch
// ---------------------------------------------------------------------------
extern "C" void kernel_launch(void* const* d_in, const int* in_sizes, int n_in,
                              void* d_out, int out_size, void* d_ws, size_t ws_size,
                              hipStream_t stream) {
    const float* hs   = (const float*)d_in[0];
    const float* cosT = (const float*)d_in[1];
    const float* sinT = (const float*)d_in[2];
    const float* WAq  = (const float*)d_in[3];
    const float* WAk  = (const float*)d_in[4];
    const float* WAv  = (const float*)d_in[5];
    const float* WBq  = (const float*)d_in[6];
    const float* WBk  = (const float*)d_in[7];
    const float* WBv  = (const float*)d_in[8];
    const float* Wo   = (const float*)d_in[9];
    const float* qnw  = (const float*)d_in[10];
    const float* knw  = (const float*)d_in[11];
    const float* kcA  = (const float*)d_in[12];
    const float* kcB  = (const float*)d_in[13];
    const float* vcA  = (const float*)d_in[14];
    const float* vcB  = (const float*)d_in[15];
    const int*   kidx = (const int*)d_in[16];
    float* out = (float*)d_out;

    const size_t MROW = (size_t)B_ * S_;   // 4096
    char* w = (char*)d_ws;
    auto alloc = [&](size_t bytes) { char* r = w; w += (bytes + 255) & ~(size_t)255; return r; };

    unsigned short* hsbf = (unsigned short*)alloc(MROW * HID_ * 2);
    unsigned short* Wt   = (unsigned short*)alloc((size_t)NPACK * HID_ * 2);
    unsigned short* Wto  = (unsigned short*)alloc((size_t)HID_ * HID_ * 2);
    float* Cp  = (float*)alloc(MROW * NPACK * 4);
    float* eKA = (float*)alloc(MROW * 16 * 4);
    float* eKB = (float*)alloc(MROW * 256 * 4);
    float* eVA = (float*)alloc(MROW * 16 * 4);
    float* eVB = (float*)alloc(MROW * 256 * 4);
    float* Qb  = (float*)alloc((size_t)B_ * NH_  * S_ * D_ * 4);
    float* Kb  = (float*)alloc((size_t)B_ * NKV_ * S_ * D_ * 4);
    float* Vb  = (float*)alloc((size_t)B_ * NKV_ * S_ * D_ * 4);
    unsigned short* aObf = (unsigned short*)alloc(MROW * (NH_ * D_) * 2);

    const int M = (int)MROW;

    // bf16 conversions / weight packing (transposed to [N][K])
    cvt_f32_bf16<<<(M * HID_ / 4 + 255) / 256, 256, 0, stream>>>(hs, hsbf, M * HID_ / 4);
    transpose_pack<<<dim3( 3, 64), 256, 0, stream>>>(WAq, HID_,   96, Wt, OFF_AQ, HID_);
    transpose_pack<<<dim3( 1, 64), 256, 0, stream>>>(WAk, HID_,   16, Wt, OFF_AK, HID_);
    transpose_pack<<<dim3( 1, 64), 256, 0, stream>>>(WAv, HID_,   16, Wt, OFF_AV, HID_);
    transpose_pack<<<dim3(24, 64), 256, 0, stream>>>(WBq, HID_,  768, Wt, OFF_BQ, HID_);
    transpose_pack<<<dim3( 8, 64), 256, 0, stream>>>(WBk, HID_,  256, Wt, OFF_BK, HID_);
    transpose_pack<<<dim3( 8, 64), 256, 0, stream>>>(WBv, HID_,  256, Wt, OFF_BV, HID_);
    transpose_pack<<<dim3(64, 64), 256, 0, stream>>>(Wo,  HID_, 2048, Wto, 0,     HID_);

    // fused projection GEMM -> Cp[4096][1408] fp32
    gemm_bf16<<<dim3(NPACK / 128, M / 128), 256, 0, stream>>>(hsbf, Wt, Cp, M, NPACK, HID_);

    // rmsnorm + rope on B_q, B_k (in place in Cp)
    norm_rope<<<M * QR_, 64, 0, stream>>>(Cp, OFF_BQ, QR_, qnw, cosT, sinT);
    norm_rope<<<M * KR_, 64, 0, stream>>>(Cp, OFF_BK, KR_, knw, cosT, sinT);

    // effective caches = input caches, scatter-updated
    hipMemcpyAsync(eKA, kcA, MROW * 16  * 4, hipMemcpyDeviceToDevice, stream);
    hipMemcpyAsync(eKB, kcB, MROW * 256 * 4, hipMemcpyDeviceToDevice, stream);
    hipMemcpyAsync(eVA, vcA, MROW * 16  * 4, hipMemcpyDeviceToDevice, stream);
    hipMemcpyAsync(eVB, vcB, MROW * 256 * 4, hipMemcpyDeviceToDevice, stream);
    scatter_kernel<<<M, 256, 0, stream>>>(Cp, kidx, eKA, eKB, eVA, eVB);

    // assemble Q/K/V (fp32)
    assemble_kernel<<<M, 256, 0, stream>>>(Cp, eKA, eKB, eVA, eVB, Qb, Kb, Vb);

    // attention -> bf16 [4096][2048]
    attn_kernel<<<dim3(S_ / 64, NH_, B_), 256, 0, stream>>>(Qb, Kb, Vb, aObf);

    // output projection -> d_out (fp32)
    gemm_bf16<<<dim3(HID_ / 128, M / 128), 256, 0, stream>>>(aObf, Wto, out, M, HID_, HID_);
}

// Round 5
// 443.567 us; speedup vs baseline: 12.2517x; 4.0809x over previous
//
#include <hip/hip_runtime.h>
#include <math.h>

#define B_    2
#define S_    2048
#define HID_  2048
#define NH_   16
#define NKV_  8
#define D_    128
#define QR_   6
#define KR_   2
#define VR_   2
#define WIN_  1024
#define CAP_  50.0f
#define EPS_  1e-6f
#define SCALE_ 0.08838834764831845f

// packed projection column offsets in Cp[4096][1408]
#define OFF_AQ 0
#define OFF_AK 96
#define OFF_AV 112
#define OFF_BQ 128
#define OFF_BK 896
#define OFF_BV 1152
#define NPACK  1408

using short8 = __attribute__((ext_vector_type(8))) short;
using f32x4  = __attribute__((ext_vector_type(4))) float;
using u16x4  = __attribute__((ext_vector_type(4))) unsigned short;

__device__ __forceinline__ unsigned short f2bf(float f) {
    union { float f; unsigned u; } v; v.f = f;
    unsigned r = v.u + 0x7FFFu + ((v.u >> 16) & 1u);   // RNE
    return (unsigned short)(r >> 16);
}

// ---------------------------------------------------------------------------
// fp32 -> bf16 elementwise (vectorized), n4 = count/4
// ---------------------------------------------------------------------------
__global__ __launch_bounds__(256) void cvt_f32_bf16(const float* __restrict__ src,
                                                    unsigned short* __restrict__ dst,
                                                    int n4) {
    int i = blockIdx.x * 256 + threadIdx.x;
    if (i < n4) {
        float4 v = ((const float4*)src)[i];
        u16x4 o;
        o[0] = f2bf(v.x); o[1] = f2bf(v.y); o[2] = f2bf(v.z); o[3] = f2bf(v.w);
        ((u16x4*)dst)[i] = o;
    }
}

// ---------------------------------------------------------------------------
// Transpose-pack: dst[(rowOff+n)*dstStride + k] = bf16(src[k*N + n])
// ---------------------------------------------------------------------------
__global__ __launch_bounds__(256) void transpose_pack(const float* __restrict__ src,
                                                      int K, int N,
                                                      unsigned short* __restrict__ dst,
                                                      int rowOff, int dstStride) {
    __shared__ float tile[32][33];
    const int k0 = blockIdx.y * 32, n0 = blockIdx.x * 32;
    const int tx = threadIdx.x & 31, ty = threadIdx.x >> 5;
#pragma unroll
    for (int i = ty; i < 32; i += 8) {
        const int k = k0 + i, n = n0 + tx;
        tile[i][tx] = (n < N) ? src[(size_t)k * N + n] : 0.f;
    }
    __syncthreads();
#pragma unroll
    for (int i = ty; i < 32; i += 8) {
        const int n = n0 + i, k = k0 + tx;
        if (n < N) dst[(size_t)(rowOff + n) * dstStride + k] = f2bf(tile[tx][i]);
    }
}

// ---------------------------------------------------------------------------
// bf16 MFMA GEMM: C[M,N] f32 = A[M,K] @ Bt[N,K]^T. (verified in round 1/2)
// ---------------------------------------------------------------------------
__global__ __launch_bounds__(256) void gemm_bf16(const unsigned short* __restrict__ A,
                                                 const unsigned short* __restrict__ Bt,
                                                 float* __restrict__ C,
                                                 int M, int N, int K) {
    __shared__ unsigned short As[4096];
    __shared__ unsigned short Bs[4096];

    const int t    = threadIdx.x;
    const int lane = t & 63, wid = t >> 6;
    const int wr = wid >> 1, wc = wid & 1;
    const int row0 = blockIdx.y * 128, col0 = blockIdx.x * 128;

    const int s0 = t, s1 = t + 256;
    const int r0 = s0 >> 2, cg0 = (s0 & 3) ^ ((r0 >> 1) & 3);
    const int r1 = s1 >> 2, cg1 = (s1 & 3) ^ ((r1 >> 1) & 3);
    const size_t aOff0 = (size_t)(row0 + r0) * K + cg0 * 8;
    const size_t aOff1 = (size_t)(row0 + r1) * K + cg1 * 8;
    const size_t bOff0 = (size_t)(col0 + r0) * K + cg0 * 8;
    const size_t bOff1 = (size_t)(col0 + r1) * K + cg1 * 8;

    f32x4 acc[4][4];
#pragma unroll
    for (int m = 0; m < 4; ++m)
#pragma unroll
        for (int n = 0; n < 4; ++n) { acc[m][n][0]=0.f; acc[m][n][1]=0.f; acc[m][n][2]=0.f; acc[m][n][3]=0.f; }

    const int l15 = lane & 15, kg = lane >> 4;
    const int rsw = ((l15 >> 1) & 3);
    int aoff[4], boff[4];
#pragma unroll
    for (int m = 0; m < 4; ++m) {
        const int ra = wr * 64 + m * 16 + l15;
        aoff[m] = ra * 32 + ((kg ^ rsw) * 8);
        const int rb = wc * 64 + m * 16 + l15;
        boff[m] = rb * 32 + ((kg ^ rsw) * 8);
    }

    for (int k0 = 0; k0 < K; k0 += 32) {
        const short8 av0 = *(const short8*)(A  + aOff0 + k0);
        const short8 av1 = *(const short8*)(A  + aOff1 + k0);
        const short8 bv0 = *(const short8*)(Bt + bOff0 + k0);
        const short8 bv1 = *(const short8*)(Bt + bOff1 + k0);
        __syncthreads();
        *(short8*)(As + s0 * 8) = av0;
        *(short8*)(As + s1 * 8) = av1;
        *(short8*)(Bs + s0 * 8) = bv0;
        *(short8*)(Bs + s1 * 8) = bv1;
        __syncthreads();
        short8 a[4], b[4];
#pragma unroll
        for (int m = 0; m < 4; ++m) a[m] = *(const short8*)(As + aoff[m]);
#pragma unroll
        for (int n = 0; n < 4; ++n) b[n] = *(const short8*)(Bs + boff[n]);
#pragma unroll
        for (int m = 0; m < 4; ++m)
#pragma unroll
            for (int n = 0; n < 4; ++n)
                acc[m][n] = __builtin_amdgcn_mfma_f32_16x16x32_bf16(a[m], b[n], acc[m][n], 0, 0, 0);
    }

#pragma unroll
    for (int m = 0; m < 4; ++m) {
#pragma unroll
        for (int n = 0; n < 4; ++n) {
            const int cc = col0 + wc * 64 + n * 16 + l15;
#pragma unroll
            for (int q = 0; q < 4; ++q) {
                const int rr = row0 + wr * 64 + m * 16 + kg * 4 + q;
                C[(size_t)rr * N + cc] = acc[m][n][q];
            }
        }
    }
}

// ---------------------------------------------------------------------------
// RMSNorm + RoPE in-place on packed Cp columns.
// ---------------------------------------------------------------------------
__global__ __launch_bounds__(64) void norm_rope(float* __restrict__ Cp,
                                                int colOff, int R,
                                                const float* __restrict__ w,
                                                const float* __restrict__ cosT,
                                                const float* __restrict__ sinT) {
    const int blk = blockIdx.x;
    const int bs = blk / R, r = blk % R;
    const int s = bs % S_;
    const int l = threadIdx.x;
    float* v = Cp + (size_t)bs * NPACK + colOff + r * D_;
    float x1 = v[l];
    float x2 = v[l + 64];
    float ss = x1 * x1 + x2 * x2;
#pragma unroll
    for (int off = 32; off; off >>= 1) ss += __shfl_xor(ss, off);
    const float inv = 1.0f / sqrtf(ss * (1.0f / 128.0f) + EPS_);
    x1 *= inv * (1.0f + w[l]);
    x2 *= inv * (1.0f + w[l + 64]);
    const float c  = cosT[s * 64 + l];
    const float sn = sinT[s * 64 + l];
    v[l]      = x1 * c - x2 * sn;
    v[l + 64] = x1 * sn + x2 * c;
}

// ---------------------------------------------------------------------------
// Scatter packed K/V factors into effective caches at kv_write_indices.
// ---------------------------------------------------------------------------
__global__ __launch_bounds__(256) void scatter_kernel(const float* __restrict__ Cp,
                                                      const int* __restrict__ idx,
                                                      float* __restrict__ eKA,
                                                      float* __restrict__ eKB,
                                                      float* __restrict__ eVA,
                                                      float* __restrict__ eVB) {
    const int bs = blockIdx.x;
    const int b  = bs / S_;
    const int s  = bs % S_;
    const int di = idx[s];
    const size_t dst = (size_t)b * S_ + di;
    const int t = threadIdx.x;
    const float* rowp = Cp + (size_t)bs * NPACK;
    if (t < 16) { eKA[dst * 16 + t] = rowp[OFF_AK + t]; eVA[dst * 16 + t] = rowp[OFF_AV + t]; }
    eKB[dst * 256 + t] = rowp[OFF_BK + t];
    eVB[dst * 256 + t] = rowp[OFF_BV + t];
}

// ---------------------------------------------------------------------------
// Assemble Q (bf16, scaled), K (bf16), V (bf16) from rank factors.
// ---------------------------------------------------------------------------
__global__ __launch_bounds__(256) void assemble_kernel(const float* __restrict__ Cp,
                                                       const float* __restrict__ eKA,
                                                       const float* __restrict__ eKB,
                                                       const float* __restrict__ eVA,
                                                       const float* __restrict__ eVB,
                                                       unsigned short* __restrict__ Qo,
                                                       unsigned short* __restrict__ Ko,
                                                       unsigned short* __restrict__ Vo) {
    __shared__ float aq[96];
    __shared__ float bq[768];
    __shared__ float ka[16];
    __shared__ float kb[256];
    __shared__ float va[16];
    __shared__ float vb[256];

    const int bs = blockIdx.x;
    const int b  = bs / S_;
    const int s  = bs % S_;
    const int t  = threadIdx.x;
    const float* rowp = Cp + (size_t)bs * NPACK;

    if (t < 96) aq[t] = rowp[OFF_AQ + t];
    for (int i = t; i < 768; i += 256) bq[i] = rowp[OFF_BQ + i];
    if (t < 16) { ka[t] = eKA[(size_t)bs * 16 + t]; va[t] = eVA[(size_t)bs * 16 + t]; }
    kb[t] = eKB[(size_t)bs * 256 + t];
    vb[t] = eVB[(size_t)bs * 256 + t];
    __syncthreads();

    const float qf = SCALE_ / (float)QR_;
#pragma unroll
    for (int i = 0; i < 8; ++i) {
        const int o = t + 256 * i;
        const int h = o >> 7, d = o & 127;
        float acc = 0.f;
#pragma unroll
        for (int r = 0; r < QR_; ++r) acc = fmaf(aq[h * QR_ + r], bq[r * D_ + d], acc);
        Qo[(((size_t)b * NH_ + h) * S_ + s) * D_ + d] = f2bf(acc * qf);
    }
#pragma unroll
    for (int i = 0; i < 4; ++i) {
        const int o = t + 256 * i;
        const int g = o >> 7, d = o & 127;
        const float kk = 0.5f * (ka[g * 2 + 0] * kb[d] + ka[g * 2 + 1] * kb[D_ + d]);
        const float vv = 0.5f * (va[g * 2 + 0] * vb[d] + va[g * 2 + 1] * vb[D_ + d]);
        Ko[(((size_t)b * NKV_ + g) * S_ + s) * D_ + d] = f2bf(kk);
        Vo[(((size_t)b * NKV_ + g) * S_ + s) * D_ + d] = f2bf(vv);
    }
}

// ---------------------------------------------------------------------------
// V [bk][s][d] bf16 -> Vt [bk][d][s] bf16, 64x64 tiles via LDS.
// ---------------------------------------------------------------------------
__global__ __launch_bounds__(256) void transpose_v(const unsigned short* __restrict__ Vn,
                                                   unsigned short* __restrict__ Vt) {
    __shared__ unsigned short ts[64][72];
    const int s0 = blockIdx.x * 64;
    const int d0 = blockIdx.y * 64;
    const int bk = blockIdx.z;
    const unsigned short* src = Vn + (size_t)bk * S_ * D_;
    unsigned short* dst = Vt + (size_t)bk * D_ * S_;
    const int t = threadIdx.x;
#pragma unroll
    for (int u = 0; u < 2; ++u) {
        const int sl = t + 256 * u;
        const int r = sl >> 3, g = sl & 7;
        *(short8*)&ts[r][g * 8] = *(const short8*)(src + (size_t)(s0 + r) * D_ + d0 + g * 8);
    }
    __syncthreads();
#pragma unroll
    for (int u = 0; u < 2; ++u) {
        const int sl = t + 256 * u;
        const int d = sl >> 3, g = sl & 7;
        short8 v;
#pragma unroll
        for (int e = 0; e < 8; ++e) v[e] = (short)ts[g * 8 + e][d];
        *(short8*)(dst + (size_t)(d0 + d) * S_ + s0 + g * 8) = v;
    }
}

// ---------------------------------------------------------------------------
// MFMA windowed causal attention with tanh soft-cap, online softmax.
// Block: 64 q-rows, 4 waves (16 rows each). K in swizzled LDS (B-frag),
// V^T in swizzled LDS (B-frag), Q frags in registers, P via 2KB wave-private
// swizzled LDS buffer. All f32 accumulation; bf16 operands.
// LDS swizzle: 16B group g of row r stored at g ^ (r&7)  (Guideline 4).
// ---------------------------------------------------------------------------
__global__ __launch_bounds__(256) void attn_mfma(const unsigned short* __restrict__ Q,
                                                 const unsigned short* __restrict__ K,
                                                 const unsigned short* __restrict__ Vt,
                                                 unsigned short* __restrict__ O) {
    __shared__ unsigned short Ks[64 * 128];    // 16 KB: key-major, 16 groups/row
    __shared__ unsigned short Vts[128 * 64];   // 16 KB: d-major, 8 groups/row
    __shared__ unsigned short Ps[4][16 * 64];  // 8 KB: per-wave P buffer

    const int qt = blockIdx.x, h = blockIdx.y, b = blockIdx.z;
    const int kv = h >> 1;                     // NH/NKV = 2
    const int q0 = qt * 64;
    const int t = threadIdx.x;
    const int lane = t & 63, wid = t >> 6;
    const int l15 = lane & 15, kg = lane >> 4;

    const unsigned short* Qb = Q  + (size_t)(b * NH_  + h)  * S_ * D_;
    const unsigned short* Kb = K  + (size_t)(b * NKV_ + kv) * S_ * D_;
    const unsigned short* Vb = Vt + (size_t)(b * NKV_ + kv) * (size_t)D_ * S_;

    // Q A-fragments: rows q0+wid*16+l15, k-chunk c -> d = c*32+kg*8
    short8 qfrag[4];
#pragma unroll
    for (int c = 0; c < 4; ++c)
        qfrag[c] = *(const short8*)(Qb + (size_t)(q0 + wid * 16 + l15) * D_ + c * 32 + kg * 8);

    // staging address precompute (pre-swizzled global source, linear LDS slot)
    int ksSlot[4], vsSlot[4];
    size_t ksSrc[4], vsSrc[4];
#pragma unroll
    for (int u = 0; u < 4; ++u) {
        const int s = t + 256 * u;
        const int key = s >> 4, gp = s & 15, g = gp ^ (key & 7);
        ksSlot[u] = s * 8;
        ksSrc[u]  = (size_t)key * D_ + g * 8;
        const int d = s >> 3, gp2 = s & 7, g2 = gp2 ^ (d & 7);
        vsSlot[u] = s * 8;
        vsSrc[u]  = (size_t)d * S_ + g2 * 8;
    }

    const int kstart  = (q0 - (WIN_ - 1) > 0) ? (q0 - (WIN_ - 1)) : 0;
    const int k_begin = kstart & ~63;
    const int nt = (q0 + 64 - k_begin) >> 6;

    short8 kreg[4], vreg[4];
#pragma unroll
    for (int u = 0; u < 4; ++u) {
        kreg[u] = *(const short8*)(Kb + (size_t)k_begin * D_ + ksSrc[u]);
        vreg[u] = *(const short8*)(Vb + (size_t)k_begin + vsSrc[u]);
    }

    float m_run[4], l_run[4];
#pragma unroll
    for (int q = 0; q < 4; ++q) { m_run[q] = -INFINITY; l_run[q] = 0.f; }
    f32x4 oacc[8];
#pragma unroll
    for (int n = 0; n < 8; ++n) { oacc[n][0] = 0.f; oacc[n][1] = 0.f; oacc[n][2] = 0.f; oacc[n][3] = 0.f; }

    unsigned short* Pw = &Ps[wid][0];
    const int gi_base = q0 + wid * 16 + kg * 4;

    for (int ti = 0; ti < nt; ++ti) {
        const int k0 = k_begin + ti * 64;
        __syncthreads();                      // prior tile's LDS reads complete
#pragma unroll
        for (int u = 0; u < 4; ++u) {
            *(short8*)(Ks  + ksSlot[u]) = kreg[u];
            *(short8*)(Vts + vsSlot[u]) = vreg[u];
        }
        __syncthreads();
        if (ti + 1 < nt) {                    // prefetch next tile (overlaps MFMA)
            const int k1 = k0 + 64;
#pragma unroll
            for (int u = 0; u < 4; ++u) {
                kreg[u] = *(const short8*)(Kb + (size_t)k1 * D_ + ksSrc[u]);
                vreg[u] = *(const short8*)(Vb + (size_t)k1 + vsSrc[u]);
            }
        }

        // ---- QK^T: S[16 rows][64 keys] per wave ----
        f32x4 sacc[4];
#pragma unroll
        for (int n = 0; n < 4; ++n) { sacc[n][0] = 0.f; sacc[n][1] = 0.f; sacc[n][2] = 0.f; sacc[n][3] = 0.f; }
#pragma unroll
        for (int c = 0; c < 4; ++c) {
#pragma unroll
            for (int n = 0; n < 4; ++n) {
                const short8 bf = *(const short8*)(Ks + (n * 16 + l15) * 128 + (((4 * c + kg) ^ (l15 & 7)) * 8));
                sacc[n] = __builtin_amdgcn_mfma_f32_16x16x32_bf16(qfrag[c], bf, sacc[n], 0, 0, 0);
            }
        }

        // ---- tanh cap + mask + online softmax (in-register) ----
        float p[4][4];     // [n][q]
        float corr[4];
#pragma unroll
        for (int q = 0; q < 4; ++q) {
            const int gi = gi_base + q;
            float sv[4];
            float tm = -INFINITY;
#pragma unroll
            for (int n = 0; n < 4; ++n) {
                const float e = __expf(sacc[n][q] * (2.0f / CAP_));
                const float v = CAP_ - (2.0f * CAP_) / (e + 1.0f);   // cap*tanh(x/cap)
                const int gj = k0 + n * 16 + l15;
                const bool ok = (gj <= gi) && (gj > gi - WIN_);
                sv[n] = ok ? v : -INFINITY;
                tm = fmaxf(tm, sv[n]);
            }
            tm = fmaxf(tm, __shfl_xor(tm, 1));
            tm = fmaxf(tm, __shfl_xor(tm, 2));
            tm = fmaxf(tm, __shfl_xor(tm, 4));
            tm = fmaxf(tm, __shfl_xor(tm, 8));
            const float mnew  = fmaxf(m_run[q], tm);
            const float msafe = (mnew > -INFINITY) ? mnew : 0.f;
            corr[q] = __expf(m_run[q] - msafe);
            float ls = 0.f;
#pragma unroll
            for (int n = 0; n < 4; ++n) {
                const float pv = __expf(sv[n] - msafe);
                p[n][q] = pv;
                ls += pv;
            }
            ls += __shfl_xor(ls, 1);
            ls += __shfl_xor(ls, 2);
            ls += __shfl_xor(ls, 4);
            ls += __shfl_xor(ls, 8);
            l_run[q] = l_run[q] * corr[q] + ls;
            m_run[q] = mnew;
        }

        // ---- P -> wave-private LDS (bf16, swizzled) ----
#pragma unroll
        for (int n = 0; n < 4; ++n)
#pragma unroll
            for (int q = 0; q < 4; ++q) {
                const int r = kg * 4 + q;
                Pw[r * 64 + (((2 * n + (l15 >> 3)) ^ (r & 7)) * 8) + (l15 & 7)] = f2bf(p[n][q]);
            }

        // ---- PV: O[16 rows][128 d] += P[16][64] * V[64][128] ----
#pragma unroll
        for (int n = 0; n < 8; ++n) {
#pragma unroll
            for (int q = 0; q < 4; ++q) oacc[n][q] *= corr[q];
        }
#pragma unroll
        for (int c = 0; c < 2; ++c) {
            const short8 af = *(const short8*)(Pw + l15 * 64 + (((4 * c + kg) ^ (l15 & 7)) * 8));
#pragma unroll
            for (int n = 0; n < 8; ++n) {
                const int d = n * 16 + l15;
                const short8 bfv = *(const short8*)(Vts + d * 64 + (((4 * c + kg) ^ (d & 7)) * 8));
                oacc[n] = __builtin_amdgcn_mfma_f32_16x16x32_bf16(af, bfv, oacc[n], 0, 0, 0);
            }
        }
    }

    // ---- epilogue ----
#pragma unroll
    for (int q = 0; q < 4; ++q) {
        const float il = (l_run[q] > 0.f) ? 1.0f / l_run[q] : 0.f;
        unsigned short* orow = O + (size_t)(b * S_ + gi_base + q) * (NH_ * D_) + h * D_;
#pragma unroll
        for (int n = 0; n < 8; ++n)
            orow[n * 16 + l15] = f2bf(oacc[n][q] * il);
    }
}

// ---------------------------------------------------------------------------
// Launch
// ---------------------------------------------------------------------------
extern "C" void kernel_launch(void* const* d_in, const int* in_sizes, int n_in,
                              void* d_out, int out_size, void* d_ws, size_t ws_size,
                              hipStream_t stream) {
    const float* hs   = (const float*)d_in[0];
    const float* cosT = (const float*)d_in[1];
    const float* sinT = (const float*)d_in[2];
    const float* WAq  = (const float*)d_in[3];
    const float* WAk  = (const float*)d_in[4];
    const float* WAv  = (const float*)d_in[5];
    const float* WBq  = (const float*)d_in[6];
    const float* WBk  = (const float*)d_in[7];
    const float* WBv  = (const float*)d_in[8];
    const float* Wo   = (const float*)d_in[9];
    const float* qnw  = (const float*)d_in[10];
    const float* knw  = (const float*)d_in[11];
    const float* kcA  = (const float*)d_in[12];
    const float* kcB  = (const float*)d_in[13];
    const float* vcA  = (const float*)d_in[14];
    const float* vcB  = (const float*)d_in[15];
    const int*   kidx = (const int*)d_in[16];
    float* out = (float*)d_out;

    const size_t MROW = (size_t)B_ * S_;   // 4096
    char* w = (char*)d_ws;
    auto alloc = [&](size_t bytes) { char* r = w; w += (bytes + 255) & ~(size_t)255; return r; };

    unsigned short* hsbf = (unsigned short*)alloc(MROW * HID_ * 2);
    unsigned short* Wt   = (unsigned short*)alloc((size_t)NPACK * HID_ * 2);
    unsigned short* Wto  = (unsigned short*)alloc((size_t)HID_ * HID_ * 2);
    float* Cp  = (float*)alloc(MROW * NPACK * 4);
    float* eKA = (float*)alloc(MROW * 16 * 4);
    float* eKB = (float*)alloc(MROW * 256 * 4);
    float* eVA = (float*)alloc(MROW * 16 * 4);
    float* eVB = (float*)alloc(MROW * 256 * 4);
    unsigned short* Qbf = (unsigned short*)alloc((size_t)B_ * NH_  * S_ * D_ * 2);
    unsigned short* Kbf = (unsigned short*)alloc((size_t)B_ * NKV_ * S_ * D_ * 2);
    unsigned short* Vbf = (unsigned short*)alloc((size_t)B_ * NKV_ * S_ * D_ * 2);
    unsigned short* Vtb = (unsigned short*)alloc((size_t)B_ * NKV_ * S_ * D_ * 2);
    unsigned short* aObf = (unsigned short*)alloc(MROW * (NH_ * D_) * 2);

    const int M = (int)MROW;

    cvt_f32_bf16<<<(M * HID_ / 4 + 255) / 256, 256, 0, stream>>>(hs, hsbf, M * HID_ / 4);
    transpose_pack<<<dim3( 3, 64), 256, 0, stream>>>(WAq, HID_,   96, Wt, OFF_AQ, HID_);
    transpose_pack<<<dim3( 1, 64), 256, 0, stream>>>(WAk, HID_,   16, Wt, OFF_AK, HID_);
    transpose_pack<<<dim3( 1, 64), 256, 0, stream>>>(WAv, HID_,   16, Wt, OFF_AV, HID_);
    transpose_pack<<<dim3(24, 64), 256, 0, stream>>>(WBq, HID_,  768, Wt, OFF_BQ, HID_);
    transpose_pack<<<dim3( 8, 64), 256, 0, stream>>>(WBk, HID_,  256, Wt, OFF_BK, HID_);
    transpose_pack<<<dim3( 8, 64), 256, 0, stream>>>(WBv, HID_,  256, Wt, OFF_BV, HID_);
    transpose_pack<<<dim3(64, 64), 256, 0, stream>>>(Wo,  HID_, 2048, Wto, 0,     HID_);

    gemm_bf16<<<dim3(NPACK / 128, M / 128), 256, 0, stream>>>(hsbf, Wt, Cp, M, NPACK, HID_);

    norm_rope<<<M * QR_, 64, 0, stream>>>(Cp, OFF_BQ, QR_, qnw, cosT, sinT);
    norm_rope<<<M * KR_, 64, 0, stream>>>(Cp, OFF_BK, KR_, knw, cosT, sinT);

    hipMemcpyAsync(eKA, kcA, MROW * 16  * 4, hipMemcpyDeviceToDevice, stream);
    hipMemcpyAsync(eKB, kcB, MROW * 256 * 4, hipMemcpyDeviceToDevice, stream);
    hipMemcpyAsync(eVA, vcA, MROW * 16  * 4, hipMemcpyDeviceToDevice, stream);
    hipMemcpyAsync(eVB, vcB, MROW * 256 * 4, hipMemcpyDeviceToDevice, stream);
    scatter_kernel<<<M, 256, 0, stream>>>(Cp, kidx, eKA, eKB, eVA, eVB);

    assemble_kernel<<<M, 256, 0, stream>>>(Cp, eKA, eKB, eVA, eVB, Qbf, Kbf, Vbf);
    transpose_v<<<dim3(S_ / 64, D_ / 64, B_ * NKV_), 256, 0, stream>>>(Vbf, Vtb);

    attn_mfma<<<dim3(S_ / 64, NH_, B_), 256, 0, stream>>>(Qbf, Kbf, Vtb, aObf);

    gemm_bf16<<<dim3(HID_ / 128, M / 128), 256, 0, stream>>>(aObf, Wto, out, M, HID_, HID_);
}

// Round 6
// 395.674 us; speedup vs baseline: 13.7346x; 1.1210x over previous
//
#include <hip/hip_runtime.h>
#include <math.h>

#define B_    2
#define S_    2048
#define HID_  2048
#define NH_   16
#define NKV_  8
#define D_    128
#define QR_   6
#define KR_   2
#define VR_   2
#define WIN_  1024
#define CAP_  50.0f
#define EPS_  1e-6f
#define SCALE_ 0.08838834764831845f

// packed projection column offsets in Cp[4096][1408]
#define OFF_AQ 0
#define OFF_AK 96
#define OFF_AV 112
#define OFF_BQ 128
#define OFF_BK 896
#define OFF_BV 1152
#define NPACK  1408

using short8 = __attribute__((ext_vector_type(8))) short;
using f32x4  = __attribute__((ext_vector_type(4))) float;
using u16x4  = __attribute__((ext_vector_type(4))) unsigned short;

__device__ __forceinline__ unsigned short f2bf(float f) {
    union { float f; unsigned u; } v; v.f = f;
    unsigned r = v.u + 0x7FFFu + ((v.u >> 16) & 1u);   // RNE
    return (unsigned short)(r >> 16);
}

// async global->LDS, 16B per lane; lds dest must be wave-uniform base (+lane*16 HW)
__device__ __forceinline__ void gload16(const unsigned short* g, unsigned short* l) {
    __builtin_amdgcn_global_load_lds(
        (const __attribute__((address_space(1))) unsigned int*)g,
        (__attribute__((address_space(3))) unsigned int*)l,
        16, 0, 0);
}

// ---------------------------------------------------------------------------
// fp32 -> bf16 elementwise (vectorized), n4 = count/4
// ---------------------------------------------------------------------------
__global__ __launch_bounds__(256) void cvt_f32_bf16(const float* __restrict__ src,
                                                    unsigned short* __restrict__ dst,
                                                    int n4) {
    int i = blockIdx.x * 256 + threadIdx.x;
    if (i < n4) {
        float4 v = ((const float4*)src)[i];
        u16x4 o;
        o[0] = f2bf(v.x); o[1] = f2bf(v.y); o[2] = f2bf(v.z); o[3] = f2bf(v.w);
        ((u16x4*)dst)[i] = o;
    }
}

// ---------------------------------------------------------------------------
// Transpose-pack: dst[(rowOff+n)*dstStride + k] = bf16(src[k*N + n])
// ---------------------------------------------------------------------------
__global__ __launch_bounds__(256) void transpose_pack(const float* __restrict__ src,
                                                      int K, int N,
                                                      unsigned short* __restrict__ dst,
                                                      int rowOff, int dstStride) {
    __shared__ float tile[32][33];
    const int k0 = blockIdx.y * 32, n0 = blockIdx.x * 32;
    const int tx = threadIdx.x & 31, ty = threadIdx.x >> 5;
#pragma unroll
    for (int i = ty; i < 32; i += 8) {
        const int k = k0 + i, n = n0 + tx;
        tile[i][tx] = (n < N) ? src[(size_t)k * N + n] : 0.f;
    }
    __syncthreads();
#pragma unroll
    for (int i = ty; i < 32; i += 8) {
        const int n = n0 + i, k = k0 + tx;
        if (n < N) dst[(size_t)(rowOff + n) * dstStride + k] = f2bf(tile[tx][i]);
    }
}

// ---------------------------------------------------------------------------
// bf16 MFMA GEMM (m97 structure): C[M,N] f32 = A[M,K] @ Bt[N,K]^T.
// 128x128 tile, BK=32, 4 waves (2x2 of 64x64), global_load_lds width=16,
// linear LDS [row][32]. M%128==0, N%128==0, K%32==0, rows 16B-aligned.
// ---------------------------------------------------------------------------
__global__ __launch_bounds__(256) void gemm_bf16(const unsigned short* __restrict__ A,
                                                 const unsigned short* __restrict__ Bt,
                                                 float* __restrict__ C,
                                                 int M, int N, int K) {
    __shared__ unsigned short As[4096];   // 128 x 32, linear
    __shared__ unsigned short Bs[4096];

    const int t    = threadIdx.x;
    const int lane = t & 63, wid = t >> 6;
    const int wr = wid >> 1, wc = wid & 1;
    const int row0 = blockIdx.y * 128, col0 = blockIdx.x * 128;

    // staging slots: slot s -> row=s>>2, kgrp=s&3; this thread serves s0=t, s1=t+256
    const int r0 = t >> 2, g0 = t & 3;
    const int r1 = r0 + 64;
    const unsigned short* aS0 = A  + (size_t)(row0 + r0) * K + g0 * 8;
    const unsigned short* aS1 = A  + (size_t)(row0 + r1) * K + g0 * 8;
    const unsigned short* bS0 = Bt + (size_t)(col0 + r0) * K + g0 * 8;
    const unsigned short* bS1 = Bt + (size_t)(col0 + r1) * K + g0 * 8;
    unsigned short* aD0 = As + wid * 512;          // wave-uniform bases
    unsigned short* aD1 = As + 2048 + wid * 512;
    unsigned short* bD0 = Bs + wid * 512;
    unsigned short* bD1 = Bs + 2048 + wid * 512;

    f32x4 acc[4][4];
#pragma unroll
    for (int m = 0; m < 4; ++m)
#pragma unroll
        for (int n = 0; n < 4; ++n) { acc[m][n][0]=0.f; acc[m][n][1]=0.f; acc[m][n][2]=0.f; acc[m][n][3]=0.f; }

    const int l15 = lane & 15, kg = lane >> 4;
    int aoff[4], boff[4];
#pragma unroll
    for (int m = 0; m < 4; ++m) {
        aoff[m] = (wr * 64 + m * 16 + l15) * 32 + kg * 8;
        boff[m] = (wc * 64 + m * 16 + l15) * 32 + kg * 8;
    }

    for (int k0 = 0; k0 < K; k0 += 32) {
        __syncthreads();                 // previous iter's LDS reads done
        gload16(aS0 + k0, aD0);
        gload16(aS1 + k0, aD1);
        gload16(bS0 + k0, bD0);
        gload16(bS1 + k0, bD1);
        __syncthreads();                 // drains vmcnt before reads
        short8 a[4], b[4];
#pragma unroll
        for (int m = 0; m < 4; ++m) a[m] = *(const short8*)(As + aoff[m]);
#pragma unroll
        for (int n = 0; n < 4; ++n) b[n] = *(const short8*)(Bs + boff[n]);
#pragma unroll
        for (int m = 0; m < 4; ++m)
#pragma unroll
            for (int n = 0; n < 4; ++n)
                acc[m][n] = __builtin_amdgcn_mfma_f32_16x16x32_bf16(a[m], b[n], acc[m][n], 0, 0, 0);
    }

#pragma unroll
    for (int m = 0; m < 4; ++m) {
#pragma unroll
        for (int n = 0; n < 4; ++n) {
            const int cc = col0 + wc * 64 + n * 16 + l15;
#pragma unroll
            for (int q = 0; q < 4; ++q) {
                const int rr = row0 + wr * 64 + m * 16 + kg * 4 + q;
                C[(size_t)rr * N + cc] = acc[m][n][q];
            }
        }
    }
}

// ---------------------------------------------------------------------------
// RMSNorm + RoPE in-place on packed Cp columns.
// ---------------------------------------------------------------------------
__global__ __launch_bounds__(64) void norm_rope(float* __restrict__ Cp,
                                                int colOff, int R,
                                                const float* __restrict__ w,
                                                const float* __restrict__ cosT,
                                                const float* __restrict__ sinT) {
    const int blk = blockIdx.x;
    const int bs = blk / R, r = blk % R;
    const int s = bs % S_;
    const int l = threadIdx.x;
    float* v = Cp + (size_t)bs * NPACK + colOff + r * D_;
    float x1 = v[l];
    float x2 = v[l + 64];
    float ss = x1 * x1 + x2 * x2;
#pragma unroll
    for (int off = 32; off; off >>= 1) ss += __shfl_xor(ss, off);
    const float inv = 1.0f / sqrtf(ss * (1.0f / 128.0f) + EPS_);
    x1 *= inv * (1.0f + w[l]);
    x2 *= inv * (1.0f + w[l + 64]);
    const float c  = cosT[s * 64 + l];
    const float sn = sinT[s * 64 + l];
    v[l]      = x1 * c - x2 * sn;
    v[l + 64] = x1 * sn + x2 * c;
}

// ---------------------------------------------------------------------------
// Scatter packed K/V factors into effective caches at kv_write_indices.
// ---------------------------------------------------------------------------
__global__ __launch_bounds__(256) void scatter_kernel(const float* __restrict__ Cp,
                                                      const int* __restrict__ idx,
                                                      float* __restrict__ eKA,
                                                      float* __restrict__ eKB,
                                                      float* __restrict__ eVA,
                                                      float* __restrict__ eVB) {
    const int bs = blockIdx.x;
    const int b  = bs / S_;
    const int s  = bs % S_;
    const int di = idx[s];
    const size_t dst = (size_t)b * S_ + di;
    const int t = threadIdx.x;
    const float* rowp = Cp + (size_t)bs * NPACK;
    if (t < 16) { eKA[dst * 16 + t] = rowp[OFF_AK + t]; eVA[dst * 16 + t] = rowp[OFF_AV + t]; }
    eKB[dst * 256 + t] = rowp[OFF_BK + t];
    eVB[dst * 256 + t] = rowp[OFF_BV + t];
}

// ---------------------------------------------------------------------------
// Assemble Q (bf16, scaled), K (bf16), V (bf16) from rank factors.
// ---------------------------------------------------------------------------
__global__ __launch_bounds__(256) void assemble_kernel(const float* __restrict__ Cp,
                                                       const float* __restrict__ eKA,
                                                       const float* __restrict__ eKB,
                                                       const float* __restrict__ eVA,
                                                       const float* __restrict__ eVB,
                                                       unsigned short* __restrict__ Qo,
                                                       unsigned short* __restrict__ Ko,
                                                       unsigned short* __restrict__ Vo) {
    __shared__ float aq[96];
    __shared__ float bq[768];
    __shared__ float ka[16];
    __shared__ float kb[256];
    __shared__ float va[16];
    __shared__ float vb[256];

    const int bs = blockIdx.x;
    const int b  = bs / S_;
    const int s  = bs % S_;
    const int t  = threadIdx.x;
    const float* rowp = Cp + (size_t)bs * NPACK;

    if (t < 96) aq[t] = rowp[OFF_AQ + t];
    for (int i = t; i < 768; i += 256) bq[i] = rowp[OFF_BQ + i];
    if (t < 16) { ka[t] = eKA[(size_t)bs * 16 + t]; va[t] = eVA[(size_t)bs * 16 + t]; }
    kb[t] = eKB[(size_t)bs * 256 + t];
    vb[t] = eVB[(size_t)bs * 256 + t];
    __syncthreads();

    const float qf = SCALE_ / (float)QR_;
#pragma unroll
    for (int i = 0; i < 8; ++i) {
        const int o = t + 256 * i;
        const int h = o >> 7, d = o & 127;
        float acc = 0.f;
#pragma unroll
        for (int r = 0; r < QR_; ++r) acc = fmaf(aq[h * QR_ + r], bq[r * D_ + d], acc);
        Qo[(((size_t)b * NH_ + h) * S_ + s) * D_ + d] = f2bf(acc * qf);
    }
#pragma unroll
    for (int i = 0; i < 4; ++i) {
        const int o = t + 256 * i;
        const int g = o >> 7, d = o & 127;
        const float kk = 0.5f * (ka[g * 2 + 0] * kb[d] + ka[g * 2 + 1] * kb[D_ + d]);
        const float vv = 0.5f * (va[g * 2 + 0] * vb[d] + va[g * 2 + 1] * vb[D_ + d]);
        Ko[(((size_t)b * NKV_ + g) * S_ + s) * D_ + d] = f2bf(kk);
        Vo[(((size_t)b * NKV_ + g) * S_ + s) * D_ + d] = f2bf(vv);
    }
}

// ---------------------------------------------------------------------------
// V [bk][s][d] bf16 -> Vt [bk][d][s] bf16, 64x64 tiles via LDS.
// ---------------------------------------------------------------------------
__global__ __launch_bounds__(256) void transpose_v(const unsigned short* __restrict__ Vn,
                                                   unsigned short* __restrict__ Vt) {
    __shared__ unsigned short ts[64][72];
    const int s0 = blockIdx.x * 64;
    const int d0 = blockIdx.y * 64;
    const int bk = blockIdx.z;
    const unsigned short* src = Vn + (size_t)bk * S_ * D_;
    unsigned short* dst = Vt + (size_t)bk * D_ * S_;
    const int t = threadIdx.x;
#pragma unroll
    for (int u = 0; u < 2; ++u) {
        const int sl = t + 256 * u;
        const int r = sl >> 3, g = sl & 7;
        *(short8*)&ts[r][g * 8] = *(const short8*)(src + (size_t)(s0 + r) * D_ + d0 + g * 8);
    }
    __syncthreads();
#pragma unroll
    for (int u = 0; u < 2; ++u) {
        const int sl = t + 256 * u;
        const int d = sl >> 3, g = sl & 7;
        short8 v;
#pragma unroll
        for (int e = 0; e < 8; ++e) v[e] = (short)ts[g * 8 + e][d];
        *(short8*)(dst + (size_t)(d0 + d) * S_ + s0 + g * 8) = v;
    }
}

// ---------------------------------------------------------------------------
// MFMA windowed causal attention, tanh soft-cap, NO-MAX softmax.
// Soft-cap bounds |sv|<=50 so exp(sv) in [1.9e-22, 5.2e21] — f32/bf16 safe.
// No running max, no corr rescale; per-lane partial l, single reduce at end.
// Block: 64 q-rows, 4 waves (16 rows each). K/V^T in swizzled LDS, Q frags
// in registers, P via wave-private swizzled LDS. f32 accumulation.
// ---------------------------------------------------------------------------
__global__ __launch_bounds__(256) void attn_mfma(const unsigned short* __restrict__ Q,
                                                 const unsigned short* __restrict__ K,
                                                 const unsigned short* __restrict__ Vt,
                                                 unsigned short* __restrict__ O) {
    __shared__ unsigned short Ks[64 * 128];    // 16 KB
    __shared__ unsigned short Vts[128 * 64];   // 16 KB
    __shared__ unsigned short Ps[4][16 * 64];  // 8 KB

    const int qt = blockIdx.x, h = blockIdx.y, b = blockIdx.z;
    const int kv = h >> 1;                     // NH/NKV = 2
    const int q0 = qt * 64;
    const int t = threadIdx.x;
    const int lane = t & 63, wid = t >> 6;
    const int l15 = lane & 15, kg = lane >> 4;

    const unsigned short* Qb = Q  + (size_t)(b * NH_  + h)  * S_ * D_;
    const unsigned short* Kb = K  + (size_t)(b * NKV_ + kv) * S_ * D_;
    const unsigned short* Vb = Vt + (size_t)(b * NKV_ + kv) * (size_t)D_ * S_;

    short8 qfrag[4];
#pragma unroll
    for (int c = 0; c < 4; ++c)
        qfrag[c] = *(const short8*)(Qb + (size_t)(q0 + wid * 16 + l15) * D_ + c * 32 + kg * 8);

    int ksSlot[4], vsSlot[4];
    size_t ksSrc[4], vsSrc[4];
#pragma unroll
    for (int u = 0; u < 4; ++u) {
        const int s = t + 256 * u;
        const int key = s >> 4, gp = s & 15, g = gp ^ (key & 7);
        ksSlot[u] = s * 8;
        ksSrc[u]  = (size_t)key * D_ + g * 8;
        const int d = s >> 3, gp2 = s & 7, g2 = gp2 ^ (d & 7);
        vsSlot[u] = s * 8;
        vsSrc[u]  = (size_t)d * S_ + g2 * 8;
    }

    const int kstart  = (q0 - (WIN_ - 1) > 0) ? (q0 - (WIN_ - 1)) : 0;
    const int k_begin = kstart & ~63;
    const int nt = (q0 + 64 - k_begin) >> 6;

    short8 kreg[4], vreg[4];
#pragma unroll
    for (int u = 0; u < 4; ++u) {
        kreg[u] = *(const short8*)(Kb + (size_t)k_begin * D_ + ksSrc[u]);
        vreg[u] = *(const short8*)(Vb + (size_t)k_begin + vsSrc[u]);
    }

    float l_run[4] = {0.f, 0.f, 0.f, 0.f};    // per-lane partial sums
    f32x4 oacc[8];
#pragma unroll
    for (int n = 0; n < 8; ++n) { oacc[n][0] = 0.f; oacc[n][1] = 0.f; oacc[n][2] = 0.f; oacc[n][3] = 0.f; }

    unsigned short* Pw = &Ps[wid][0];
    const int gi_base = q0 + wid * 16 + kg * 4;

    for (int ti = 0; ti < nt; ++ti) {
        const int k0 = k_begin + ti * 64;
        __syncthreads();
#pragma unroll
        for (int u = 0; u < 4; ++u) {
            *(short8*)(Ks  + ksSlot[u]) = kreg[u];
            *(short8*)(Vts + vsSlot[u]) = vreg[u];
        }
        __syncthreads();
        if (ti + 1 < nt) {
            const int k1 = k0 + 64;
#pragma unroll
            for (int u = 0; u < 4; ++u) {
                kreg[u] = *(const short8*)(Kb + (size_t)k1 * D_ + ksSrc[u]);
                vreg[u] = *(const short8*)(Vb + (size_t)k1 + vsSrc[u]);
            }
        }

        // ---- QK^T ----
        f32x4 sacc[4];
#pragma unroll
        for (int n = 0; n < 4; ++n) { sacc[n][0] = 0.f; sacc[n][1] = 0.f; sacc[n][2] = 0.f; sacc[n][3] = 0.f; }
#pragma unroll
        for (int c = 0; c < 4; ++c) {
#pragma unroll
            for (int n = 0; n < 4; ++n) {
                const short8 bf = *(const short8*)(Ks + (n * 16 + l15) * 128 + (((4 * c + kg) ^ (l15 & 7)) * 8));
                sacc[n] = __builtin_amdgcn_mfma_f32_16x16x32_bf16(qfrag[c], bf, sacc[n], 0, 0, 0);
            }
        }

        // ---- tanh cap + mask + no-max exp: p = exp(CAP - 2*CAP/(e+1)) ----
        float p[4][4];
#pragma unroll
        for (int q = 0; q < 4; ++q) {
            const int gi = gi_base + q;
#pragma unroll
            for (int n = 0; n < 4; ++n) {
                const float e  = __expf(sacc[n][q] * (2.0f / CAP_));
                const float r  = __builtin_amdgcn_rcpf(e + 1.0f);
                const int  gj  = k0 + n * 16 + l15;
                const bool ok  = (gj <= gi) && (gj > gi - WIN_);
                const float pv = ok ? __expf(fmaf(-2.0f * CAP_, r, CAP_)) : 0.f;
                p[n][q] = pv;
                l_run[q] += pv;
            }
        }

        // ---- P -> wave-private LDS (bf16, swizzled) ----
#pragma unroll
        for (int n = 0; n < 4; ++n)
#pragma unroll
            for (int q = 0; q < 4; ++q) {
                const int r = kg * 4 + q;
                Pw[r * 64 + (((2 * n + (l15 >> 3)) ^ (r & 7)) * 8) + (l15 & 7)] = f2bf(p[n][q]);
            }

        // ---- PV (no rescale needed) ----
#pragma unroll
        for (int c = 0; c < 2; ++c) {
            const short8 af = *(const short8*)(Pw + l15 * 64 + (((4 * c + kg) ^ (l15 & 7)) * 8));
#pragma unroll
            for (int n = 0; n < 8; ++n) {
                const int d = n * 16 + l15;
                const short8 bfv = *(const short8*)(Vts + d * 64 + (((4 * c + kg) ^ (d & 7)) * 8));
                oacc[n] = __builtin_amdgcn_mfma_f32_16x16x32_bf16(af, bfv, oacc[n], 0, 0, 0);
            }
        }
    }

    // ---- epilogue: reduce l across the 16-lane row group, normalize ----
#pragma unroll
    for (int q = 0; q < 4; ++q) {
        float ls = l_run[q];
        ls += __shfl_xor(ls, 1);
        ls += __shfl_xor(ls, 2);
        ls += __shfl_xor(ls, 4);
        ls += __shfl_xor(ls, 8);
        const float il = (ls > 0.f) ? 1.0f / ls : 0.f;
        unsigned short* orow = O + (size_t)(b * S_ + gi_base + q) * (NH_ * D_) + h * D_;
#pragma unroll
        for (int n = 0; n < 8; ++n)
            orow[n * 16 + l15] = f2bf(oacc[n][q] * il);
    }
}

// ---------------------------------------------------------------------------
// Launch
// ---------------------------------------------------------------------------
extern "C" void kernel_launch(void* const* d_in, const int* in_sizes, int n_in,
                              void* d_out, int out_size, void* d_ws, size_t ws_size,
                              hipStream_t stream) {
    const float* hs   = (const float*)d_in[0];
    const float* cosT = (const float*)d_in[1];
    const float* sinT = (const float*)d_in[2];
    const float* WAq  = (const float*)d_in[3];
    const float* WAk  = (const float*)d_in[4];
    const float* WAv  = (const float*)d_in[5];
    const float* WBq  = (const float*)d_in[6];
    const float* WBk  = (const float*)d_in[7];
    const float* WBv  = (const float*)d_in[8];
    const float* Wo   = (const float*)d_in[9];
    const float* qnw  = (const float*)d_in[10];
    const float* knw  = (const float*)d_in[11];
    const float* kcA  = (const float*)d_in[12];
    const float* kcB  = (const float*)d_in[13];
    const float* vcA  = (const float*)d_in[14];
    const float* vcB  = (const float*)d_in[15];
    const int*   kidx = (const int*)d_in[16];
    float* out = (float*)d_out;

    const size_t MROW = (size_t)B_ * S_;   // 4096
    char* w = (char*)d_ws;
    auto alloc = [&](size_t bytes) { char* r = w; w += (bytes + 255) & ~(size_t)255; return r; };

    unsigned short* hsbf = (unsigned short*)alloc(MROW * HID_ * 2);
    unsigned short* Wt   = (unsigned short*)alloc((size_t)NPACK * HID_ * 2);
    unsigned short* Wto  = (unsigned short*)alloc((size_t)HID_ * HID_ * 2);
    float* Cp  = (float*)alloc(MROW * NPACK * 4);
    float* eKA = (float*)alloc(MROW * 16 * 4);
    float* eKB = (float*)alloc(MROW * 256 * 4);
    float* eVA = (float*)alloc(MROW * 16 * 4);
    float* eVB = (float*)alloc(MROW * 256 * 4);
    unsigned short* Qbf = (unsigned short*)alloc((size_t)B_ * NH_  * S_ * D_ * 2);
    unsigned short* Kbf = (unsigned short*)alloc((size_t)B_ * NKV_ * S_ * D_ * 2);
    unsigned short* Vbf = (unsigned short*)alloc((size_t)B_ * NKV_ * S_ * D_ * 2);
    unsigned short* Vtb = (unsigned short*)alloc((size_t)B_ * NKV_ * S_ * D_ * 2);
    unsigned short* aObf = (unsigned short*)alloc(MROW * (NH_ * D_) * 2);

    const int M = (int)MROW;

    cvt_f32_bf16<<<(M * HID_ / 4 + 255) / 256, 256, 0, stream>>>(hs, hsbf, M * HID_ / 4);
    transpose_pack<<<dim3( 3, 64), 256, 0, stream>>>(WAq, HID_,   96, Wt, OFF_AQ, HID_);
    transpose_pack<<<dim3( 1, 64), 256, 0, stream>>>(WAk, HID_,   16, Wt, OFF_AK, HID_);
    transpose_pack<<<dim3( 1, 64), 256, 0, stream>>>(WAv, HID_,   16, Wt, OFF_AV, HID_);
    transpose_pack<<<dim3(24, 64), 256, 0, stream>>>(WBq, HID_,  768, Wt, OFF_BQ, HID_);
    transpose_pack<<<dim3( 8, 64), 256, 0, stream>>>(WBk, HID_,  256, Wt, OFF_BK, HID_);
    transpose_pack<<<dim3( 8, 64), 256, 0, stream>>>(WBv, HID_,  256, Wt, OFF_BV, HID_);
    transpose_pack<<<dim3(64, 64), 256, 0, stream>>>(Wo,  HID_, 2048, Wto, 0,     HID_);

    gemm_bf16<<<dim3(NPACK / 128, M / 128), 256, 0, stream>>>(hsbf, Wt, Cp, M, NPACK, HID_);

    norm_rope<<<M * QR_, 64, 0, stream>>>(Cp, OFF_BQ, QR_, qnw, cosT, sinT);
    norm_rope<<<M * KR_, 64, 0, stream>>>(Cp, OFF_BK, KR_, knw, cosT, sinT);

    hipMemcpyAsync(eKA, kcA, MROW * 16  * 4, hipMemcpyDeviceToDevice, stream);
    hipMemcpyAsync(eKB, kcB, MROW * 256 * 4, hipMemcpyDeviceToDevice, stream);
    hipMemcpyAsync(eVA, vcA, MROW * 16  * 4, hipMemcpyDeviceToDevice, stream);
    hipMemcpyAsync(eVB, vcB, MROW * 256 * 4, hipMemcpyDeviceToDevice, stream);
    scatter_kernel<<<M, 256, 0, stream>>>(Cp, kidx, eKA, eKB, eVA, eVB);

    assemble_kernel<<<M, 256, 0, stream>>>(Cp, eKA, eKB, eVA, eVB, Qbf, Kbf, Vbf);
    transpose_v<<<dim3(S_ / 64, D_ / 64, B_ * NKV_), 256, 0, stream>>>(Vbf, Vtb);

    attn_mfma<<<dim3(S_ / 64, NH_, B_), 256, 0, stream>>>(Qbf, Kbf, Vtb, aObf);

    gemm_bf16<<<dim3(HID_ / 128, M / 128), 256, 0, stream>>>(aObf, Wto, out, M, HID_, HID_);
}

// Round 7
// 372.635 us; speedup vs baseline: 14.5838x; 1.0618x over previous
//
#include <hip/hip_runtime.h>
#include <math.h>

#define B_    2
#define S_    2048
#define HID_  2048
#define NH_   16
#define NKV_  8
#define D_    128
#define QR_   6
#define KR_   2
#define VR_   2
#define WIN_  1024
#define CAP_  50.0f
#define EPS_  1e-6f
#define SCALE_ 0.08838834764831845f

// packed projection column offsets in Cp[4096][1408]
#define OFF_AQ 0
#define OFF_AK 96
#define OFF_AV 112
#define OFF_BQ 128
#define OFF_BK 896
#define OFF_BV 1152
#define NPACK  1408

using short8 = __attribute__((ext_vector_type(8))) short;
using f32x4  = __attribute__((ext_vector_type(4))) float;
using u16x4  = __attribute__((ext_vector_type(4))) unsigned short;

__device__ __forceinline__ unsigned short f2bf(float f) {
    union { float f; unsigned u; } v; v.f = f;
    unsigned r = v.u + 0x7FFFu + ((v.u >> 16) & 1u);   // RNE
    return (unsigned short)(r >> 16);
}

// async global->LDS, 16B per lane; lds dest is wave-uniform base (+lane*16 HW)
__device__ __forceinline__ void gload16(const unsigned short* g, unsigned short* l) {
    __builtin_amdgcn_global_load_lds(
        (const __attribute__((address_space(1))) unsigned int*)g,
        (__attribute__((address_space(3))) unsigned int*)l,
        16, 0, 0);
}

// ---------------------------------------------------------------------------
// fp32 -> bf16 elementwise (vectorized), n4 = count/4
// ---------------------------------------------------------------------------
__global__ __launch_bounds__(256) void cvt_f32_bf16(const float* __restrict__ src,
                                                    unsigned short* __restrict__ dst,
                                                    int n4) {
    int i = blockIdx.x * 256 + threadIdx.x;
    if (i < n4) {
        float4 v = ((const float4*)src)[i];
        u16x4 o;
        o[0] = f2bf(v.x); o[1] = f2bf(v.y); o[2] = f2bf(v.z); o[3] = f2bf(v.w);
        ((u16x4*)dst)[i] = o;
    }
}

// ---------------------------------------------------------------------------
// All 7 weight transpose-packs in ONE dispatch (z = segment).
// dst[(rowOff+n)*HID + k] = bf16(src[k*N + n]);  K = HID for all segments.
// ---------------------------------------------------------------------------
__global__ __launch_bounds__(256) void pack_weights(const float* __restrict__ s0,
                                                    const float* __restrict__ s1,
                                                    const float* __restrict__ s2,
                                                    const float* __restrict__ s3,
                                                    const float* __restrict__ s4,
                                                    const float* __restrict__ s5,
                                                    const float* __restrict__ s6,
                                                    unsigned short* __restrict__ Wt,
                                                    unsigned short* __restrict__ Wto) {
    __shared__ float tile[32][33];
    const int seg = blockIdx.z;
    const float* src; int N, rowOff; unsigned short* dst;
    switch (seg) {
        case 0:  src = s0; N =   96; rowOff = OFF_AQ; dst = Wt;  break;
        case 1:  src = s1; N =   16; rowOff = OFF_AK; dst = Wt;  break;
        case 2:  src = s2; N =   16; rowOff = OFF_AV; dst = Wt;  break;
        case 3:  src = s3; N =  768; rowOff = OFF_BQ; dst = Wt;  break;
        case 4:  src = s4; N =  256; rowOff = OFF_BK; dst = Wt;  break;
        case 5:  src = s5; N =  256; rowOff = OFF_BV; dst = Wt;  break;
        default: src = s6; N = 2048; rowOff = 0;      dst = Wto; break;
    }
    const int n0 = blockIdx.x * 32;
    if (n0 >= N) return;
    const int k0 = blockIdx.y * 32;
    const int tx = threadIdx.x & 31, ty = threadIdx.x >> 5;
#pragma unroll
    for (int i = ty; i < 32; i += 8) {
        const int k = k0 + i, n = n0 + tx;
        tile[i][tx] = (n < N) ? src[(size_t)k * N + n] : 0.f;
    }
    __syncthreads();
#pragma unroll
    for (int i = ty; i < 32; i += 8) {
        const int n = n0 + i, k = k0 + tx;
        if (n < N) dst[(size_t)(rowOff + n) * HID_ + k] = f2bf(tile[tx][i]);
    }
}

// ---------------------------------------------------------------------------
// bf16 MFMA GEMM (m97 structure): C[M,N] f32 = A[M,K] @ Bt[N,K]^T.
// 128x128 tile, BK=32, 4 waves, global_load_lds width=16, linear LDS.
// ---------------------------------------------------------------------------
__global__ __launch_bounds__(256) void gemm_bf16(const unsigned short* __restrict__ A,
                                                 const unsigned short* __restrict__ Bt,
                                                 float* __restrict__ C,
                                                 int M, int N, int K) {
    __shared__ unsigned short As[4096];   // 128 x 32, linear
    __shared__ unsigned short Bs[4096];

    const int t    = threadIdx.x;
    const int lane = t & 63, wid = t >> 6;
    const int wr = wid >> 1, wc = wid & 1;
    const int row0 = blockIdx.y * 128, col0 = blockIdx.x * 128;

    const int r0 = t >> 2, g0 = t & 3;
    const int r1 = r0 + 64;
    const unsigned short* aS0 = A  + (size_t)(row0 + r0) * K + g0 * 8;
    const unsigned short* aS1 = A  + (size_t)(row0 + r1) * K + g0 * 8;
    const unsigned short* bS0 = Bt + (size_t)(col0 + r0) * K + g0 * 8;
    const unsigned short* bS1 = Bt + (size_t)(col0 + r1) * K + g0 * 8;
    unsigned short* aD0 = As + wid * 512;          // wave-uniform bases
    unsigned short* aD1 = As + 2048 + wid * 512;
    unsigned short* bD0 = Bs + wid * 512;
    unsigned short* bD1 = Bs + 2048 + wid * 512;

    f32x4 acc[4][4];
#pragma unroll
    for (int m = 0; m < 4; ++m)
#pragma unroll
        for (int n = 0; n < 4; ++n) { acc[m][n][0]=0.f; acc[m][n][1]=0.f; acc[m][n][2]=0.f; acc[m][n][3]=0.f; }

    const int l15 = lane & 15, kg = lane >> 4;
    int aoff[4], boff[4];
#pragma unroll
    for (int m = 0; m < 4; ++m) {
        aoff[m] = (wr * 64 + m * 16 + l15) * 32 + kg * 8;
        boff[m] = (wc * 64 + m * 16 + l15) * 32 + kg * 8;
    }

    for (int k0 = 0; k0 < K; k0 += 32) {
        __syncthreads();
        gload16(aS0 + k0, aD0);
        gload16(aS1 + k0, aD1);
        gload16(bS0 + k0, bD0);
        gload16(bS1 + k0, bD1);
        __syncthreads();
        short8 a[4], b[4];
#pragma unroll
        for (int m = 0; m < 4; ++m) a[m] = *(const short8*)(As + aoff[m]);
#pragma unroll
        for (int n = 0; n < 4; ++n) b[n] = *(const short8*)(Bs + boff[n]);
#pragma unroll
        for (int m = 0; m < 4; ++m)
#pragma unroll
            for (int n = 0; n < 4; ++n)
                acc[m][n] = __builtin_amdgcn_mfma_f32_16x16x32_bf16(a[m], b[n], acc[m][n], 0, 0, 0);
    }

#pragma unroll
    for (int m = 0; m < 4; ++m) {
#pragma unroll
        for (int n = 0; n < 4; ++n) {
            const int cc = col0 + wc * 64 + n * 16 + l15;
#pragma unroll
            for (int q = 0; q < 4; ++q) {
                const int rr = row0 + wr * 64 + m * 16 + kg * 4 + q;
                C[(size_t)rr * N + cc] = acc[m][n][q];
            }
        }
    }
}

// ---------------------------------------------------------------------------
// RMSNorm + RoPE for BOTH q (y=0) and k (y=1) in one dispatch.
// ---------------------------------------------------------------------------
__global__ __launch_bounds__(64) void norm_rope_all(float* __restrict__ Cp,
                                                    const float* __restrict__ qnw,
                                                    const float* __restrict__ knw,
                                                    const float* __restrict__ cosT,
                                                    const float* __restrict__ sinT) {
    const int which = blockIdx.y;
    const int R = which ? KR_ : QR_;
    const int blk = blockIdx.x;
    if (blk >= B_ * S_ * R) return;
    const int colOff = which ? OFF_BK : OFF_BQ;
    const float* w = which ? knw : qnw;
    const int bs = blk / R, r = blk % R;
    const int s = bs % S_;
    const int l = threadIdx.x;
    float* v = Cp + (size_t)bs * NPACK + colOff + r * D_;
    float x1 = v[l];
    float x2 = v[l + 64];
    float ss = x1 * x1 + x2 * x2;
#pragma unroll
    for (int off = 32; off; off >>= 1) ss += __shfl_xor(ss, off);
    const float inv = 1.0f / sqrtf(ss * (1.0f / 128.0f) + EPS_);
    x1 *= inv * (1.0f + w[l]);
    x2 *= inv * (1.0f + w[l + 64]);
    const float c  = cosT[s * 64 + l];
    const float sn = sinT[s * 64 + l];
    v[l]      = x1 * c - x2 * sn;
    v[l + 64] = x1 * sn + x2 * c;
}

// ---------------------------------------------------------------------------
// Copy the 4 input caches into effective caches in ONE dispatch (float4).
// ---------------------------------------------------------------------------
__global__ __launch_bounds__(256) void copy_caches(const float4* __restrict__ kA,
                                                   const float4* __restrict__ kB,
                                                   const float4* __restrict__ vA,
                                                   const float4* __restrict__ vB,
                                                   float4* __restrict__ eA,
                                                   float4* __restrict__ eB,
                                                   float4* __restrict__ eC,
                                                   float4* __restrict__ eD) {
    const int NA = B_ * S_ * 16 / 4;    // 16384
    const int NB = B_ * S_ * 256 / 4;   // 262144
    int i = blockIdx.x * 256 + threadIdx.x;
    if (i < NA)                { eA[i] = kA[i]; return; }
    i -= NA;
    if (i < NB)                { eB[i] = kB[i]; return; }
    i -= NB;
    if (i < NA)                { eC[i] = vA[i]; return; }
    i -= NA;
    if (i < NB)                { eD[i] = vB[i]; }
}

// ---------------------------------------------------------------------------
// Scatter packed K/V factors into effective caches at kv_write_indices.
// ---------------------------------------------------------------------------
__global__ __launch_bounds__(256) void scatter_kernel(const float* __restrict__ Cp,
                                                      const int* __restrict__ idx,
                                                      float* __restrict__ eKA,
                                                      float* __restrict__ eKB,
                                                      float* __restrict__ eVA,
                                                      float* __restrict__ eVB) {
    const int bs = blockIdx.x;
    const int b  = bs / S_;
    const int s  = bs % S_;
    const int di = idx[s];
    const size_t dst = (size_t)b * S_ + di;
    const int t = threadIdx.x;
    const float* rowp = Cp + (size_t)bs * NPACK;
    if (t < 16) { eKA[dst * 16 + t] = rowp[OFF_AK + t]; eVA[dst * 16 + t] = rowp[OFF_AV + t]; }
    eKB[dst * 256 + t] = rowp[OFF_BK + t];
    eVB[dst * 256 + t] = rowp[OFF_BV + t];
}

// ---------------------------------------------------------------------------
// Assemble Q (bf16, scaled), K (bf16), V (bf16) from rank factors.
// ---------------------------------------------------------------------------
__global__ __launch_bounds__(256) void assemble_kernel(const float* __restrict__ Cp,
                                                       const float* __restrict__ eKA,
                                                       const float* __restrict__ eKB,
                                                       const float* __restrict__ eVA,
                                                       const float* __restrict__ eVB,
                                                       unsigned short* __restrict__ Qo,
                                                       unsigned short* __restrict__ Ko,
                                                       unsigned short* __restrict__ Vo) {
    __shared__ float aq[96];
    __shared__ float bq[768];
    __shared__ float ka[16];
    __shared__ float kb[256];
    __shared__ float va[16];
    __shared__ float vb[256];

    const int bs = blockIdx.x;
    const int b  = bs / S_;
    const int s  = bs % S_;
    const int t  = threadIdx.x;
    const float* rowp = Cp + (size_t)bs * NPACK;

    if (t < 96) aq[t] = rowp[OFF_AQ + t];
    for (int i = t; i < 768; i += 256) bq[i] = rowp[OFF_BQ + i];
    if (t < 16) { ka[t] = eKA[(size_t)bs * 16 + t]; va[t] = eVA[(size_t)bs * 16 + t]; }
    kb[t] = eKB[(size_t)bs * 256 + t];
    vb[t] = eVB[(size_t)bs * 256 + t];
    __syncthreads();

    const float qf = SCALE_ / (float)QR_;
#pragma unroll
    for (int i = 0; i < 8; ++i) {
        const int o = t + 256 * i;
        const int h = o >> 7, d = o & 127;
        float acc = 0.f;
#pragma unroll
        for (int r = 0; r < QR_; ++r) acc = fmaf(aq[h * QR_ + r], bq[r * D_ + d], acc);
        Qo[(((size_t)b * NH_ + h) * S_ + s) * D_ + d] = f2bf(acc * qf);
    }
#pragma unroll
    for (int i = 0; i < 4; ++i) {
        const int o = t + 256 * i;
        const int g = o >> 7, d = o & 127;
        const float kk = 0.5f * (ka[g * 2 + 0] * kb[d] + ka[g * 2 + 1] * kb[D_ + d]);
        const float vv = 0.5f * (va[g * 2 + 0] * vb[d] + va[g * 2 + 1] * vb[D_ + d]);
        Ko[(((size_t)b * NKV_ + g) * S_ + s) * D_ + d] = f2bf(kk);
        Vo[(((size_t)b * NKV_ + g) * S_ + s) * D_ + d] = f2bf(vv);
    }
}

// ---------------------------------------------------------------------------
// V [bk][s][d] bf16 -> Vt [bk][d][s] bf16.  64s x 128d tile per block.
// Pair-packed transpose: two s per u32, XOR-swizzled [128][36] u32 LDS.
// Writes: 2-way max (free). Reads: b128 at the LDS floor. All I/O 16B.
// ---------------------------------------------------------------------------
__global__ __launch_bounds__(256) void transpose_v(const unsigned short* __restrict__ Vn,
                                                   unsigned short* __restrict__ Vt) {
    __shared__ unsigned int ts32[128][36];    // row stride 36 u32 (16B-aligned rows)
    const int s0 = blockIdx.x * 64;
    const int bk = blockIdx.z;
    const unsigned short* src = Vn + (size_t)bk * S_ * D_;
    unsigned short* dst = Vt + (size_t)bk * D_ * S_;
    const int t = threadIdx.x;
    const int dg  = t & 15;      // d-group (8 d each)
    const int spq = t >> 4;      // s-pair within half

#pragma unroll
    for (int u = 0; u < 2; ++u) {
        const int sp = u * 16 + spq;   // s-pair 0..31
        const short8 a = *(const short8*)(src + (size_t)(s0 + 2 * sp)     * D_ + dg * 8);
        const short8 b = *(const short8*)(src + (size_t)(s0 + 2 * sp + 1) * D_ + dg * 8);
#pragma unroll
        for (int e = 0; e < 8; ++e) {
            const int d = dg * 8 + e;
            const unsigned int val = ((unsigned int)(unsigned short)a[e])
                                   | (((unsigned int)(unsigned short)b[e]) << 16);
            ts32[d][sp ^ (4 * (dg & 7))] = val;
        }
    }
    __syncthreads();
#pragma unroll
    for (int u = 0; u < 4; ++u) {
        const int slot = t + 256 * u;
        const int d = slot >> 3, sg = slot & 7;
        const int cb = (sg * 4) ^ (4 * ((d >> 3) & 7));
        const uint4 v = *(const uint4*)&ts32[d][cb];
        short8 o;
        o[0] = (short)(v.x & 0xffff); o[1] = (short)(v.x >> 16);
        o[2] = (short)(v.y & 0xffff); o[3] = (short)(v.y >> 16);
        o[4] = (short)(v.z & 0xffff); o[5] = (short)(v.z >> 16);
        o[6] = (short)(v.w & 0xffff); o[7] = (short)(v.w >> 16);
        *(short8*)(dst + (size_t)d * S_ + s0 + sg * 8) = o;
    }
}

// ---------------------------------------------------------------------------
// MFMA windowed causal attention, tanh soft-cap, NO-MAX softmax.
// Grid (hb=32, qt=32): h = x&15, b = x>>4, qt = 31 - y (longest-first).
// This spreads tile-counts evenly across CUs (x-major dispatch, 1024 blocks
// on 256 CUs: same-CU blocks differ in qt by 8 -> balanced 44..58 tiles).
// ---------------------------------------------------------------------------
__global__ __launch_bounds__(256) void attn_mfma(const unsigned short* __restrict__ Q,
                                                 const unsigned short* __restrict__ K,
                                                 const unsigned short* __restrict__ Vt,
                                                 unsigned short* __restrict__ O) {
    __shared__ unsigned short Ks[64 * 128];    // 16 KB
    __shared__ unsigned short Vts[128 * 64];   // 16 KB
    __shared__ unsigned short Ps[4][16 * 64];  // 8 KB

    const int hb = blockIdx.x;
    const int h = hb & 15, b = hb >> 4;
    const int qt = 31 - (int)blockIdx.y;
    const int kv = h >> 1;                     // NH/NKV = 2
    const int q0 = qt * 64;
    const int t = threadIdx.x;
    const int lane = t & 63, wid = t >> 6;
    const int l15 = lane & 15, kg = lane >> 4;

    const unsigned short* Qb = Q  + (size_t)(b * NH_  + h)  * S_ * D_;
    const unsigned short* Kb = K  + (size_t)(b * NKV_ + kv) * S_ * D_;
    const unsigned short* Vb = Vt + (size_t)(b * NKV_ + kv) * (size_t)D_ * S_;

    short8 qfrag[4];
#pragma unroll
    for (int c = 0; c < 4; ++c)
        qfrag[c] = *(const short8*)(Qb + (size_t)(q0 + wid * 16 + l15) * D_ + c * 32 + kg * 8);

    int ksSlot[4], vsSlot[4];
    size_t ksSrc[4], vsSrc[4];
#pragma unroll
    for (int u = 0; u < 4; ++u) {
        const int s = t + 256 * u;
        const int key = s >> 4, gp = s & 15, g = gp ^ (key & 7);
        ksSlot[u] = s * 8;
        ksSrc[u]  = (size_t)key * D_ + g * 8;
        const int d = s >> 3, gp2 = s & 7, g2 = gp2 ^ (d & 7);
        vsSlot[u] = s * 8;
        vsSrc[u]  = (size_t)d * S_ + g2 * 8;
    }

    const int kstart  = (q0 - (WIN_ - 1) > 0) ? (q0 - (WIN_ - 1)) : 0;
    const int k_begin = kstart & ~63;
    const int nt = (q0 + 64 - k_begin) >> 6;

    short8 kreg[4], vreg[4];
#pragma unroll
    for (int u = 0; u < 4; ++u) {
        kreg[u] = *(const short8*)(Kb + (size_t)k_begin * D_ + ksSrc[u]);
        vreg[u] = *(const short8*)(Vb + (size_t)k_begin + vsSrc[u]);
    }

    float l_run[4] = {0.f, 0.f, 0.f, 0.f};
    f32x4 oacc[8];
#pragma unroll
    for (int n = 0; n < 8; ++n) { oacc[n][0] = 0.f; oacc[n][1] = 0.f; oacc[n][2] = 0.f; oacc[n][3] = 0.f; }

    unsigned short* Pw = &Ps[wid][0];
    const int gi_base = q0 + wid * 16 + kg * 4;

    for (int ti = 0; ti < nt; ++ti) {
        const int k0 = k_begin + ti * 64;
        __syncthreads();
#pragma unroll
        for (int u = 0; u < 4; ++u) {
            *(short8*)(Ks  + ksSlot[u]) = kreg[u];
            *(short8*)(Vts + vsSlot[u]) = vreg[u];
        }
        __syncthreads();
        if (ti + 1 < nt) {
            const int k1 = k0 + 64;
#pragma unroll
            for (int u = 0; u < 4; ++u) {
                kreg[u] = *(const short8*)(Kb + (size_t)k1 * D_ + ksSrc[u]);
                vreg[u] = *(const short8*)(Vb + (size_t)k1 + vsSrc[u]);
            }
        }

        // ---- QK^T ----
        f32x4 sacc[4];
#pragma unroll
        for (int n = 0; n < 4; ++n) { sacc[n][0] = 0.f; sacc[n][1] = 0.f; sacc[n][2] = 0.f; sacc[n][3] = 0.f; }
#pragma unroll
        for (int c = 0; c < 4; ++c) {
#pragma unroll
            for (int n = 0; n < 4; ++n) {
                const short8 bf = *(const short8*)(Ks + (n * 16 + l15) * 128 + (((4 * c + kg) ^ (l15 & 7)) * 8));
                sacc[n] = __builtin_amdgcn_mfma_f32_16x16x32_bf16(qfrag[c], bf, sacc[n], 0, 0, 0);
            }
        }

        // ---- tanh cap + mask + no-max exp: p = exp(CAP - 2*CAP/(e+1)) ----
        float p[4][4];
#pragma unroll
        for (int q = 0; q < 4; ++q) {
            const int gi = gi_base + q;
#pragma unroll
            for (int n = 0; n < 4; ++n) {
                const float e  = __expf(sacc[n][q] * (2.0f / CAP_));
                const float r  = __builtin_amdgcn_rcpf(e + 1.0f);
                const int  gj  = k0 + n * 16 + l15;
                const bool ok  = (gj <= gi) && (gj > gi - WIN_);
                const float pv = ok ? __expf(fmaf(-2.0f * CAP_, r, CAP_)) : 0.f;
                p[n][q] = pv;
                l_run[q] += pv;
            }
        }

        // ---- P -> wave-private LDS (bf16, swizzled) ----
#pragma unroll
        for (int n = 0; n < 4; ++n)
#pragma unroll
            for (int q = 0; q < 4; ++q) {
                const int r = kg * 4 + q;
                Pw[r * 64 + (((2 * n + (l15 >> 3)) ^ (r & 7)) * 8) + (l15 & 7)] = f2bf(p[n][q]);
            }

        // ---- PV ----
#pragma unroll
        for (int c = 0; c < 2; ++c) {
            const short8 af = *(const short8*)(Pw + l15 * 64 + (((4 * c + kg) ^ (l15 & 7)) * 8));
#pragma unroll
            for (int n = 0; n < 8; ++n) {
                const int d = n * 16 + l15;
                const short8 bfv = *(const short8*)(Vts + d * 64 + (((4 * c + kg) ^ (d & 7)) * 8));
                oacc[n] = __builtin_amdgcn_mfma_f32_16x16x32_bf16(af, bfv, oacc[n], 0, 0, 0);
            }
        }
    }

    // ---- epilogue ----
#pragma unroll
    for (int q = 0; q < 4; ++q) {
        float ls = l_run[q];
        ls += __shfl_xor(ls, 1);
        ls += __shfl_xor(ls, 2);
        ls += __shfl_xor(ls, 4);
        ls += __shfl_xor(ls, 8);
        const float il = (ls > 0.f) ? 1.0f / ls : 0.f;
        unsigned short* orow = O + (size_t)(b * S_ + gi_base + q) * (NH_ * D_) + h * D_;
#pragma unroll
        for (int n = 0; n < 8; ++n)
            orow[n * 16 + l15] = f2bf(oacc[n][q] * il);
    }
}

// ---------------------------------------------------------------------------
// Launch
// ---------------------------------------------------------------------------
extern "C" void kernel_launch(void* const* d_in, const int* in_sizes, int n_in,
                              void* d_out, int out_size, void* d_ws, size_t ws_size,
                              hipStream_t stream) {
    const float* hs   = (const float*)d_in[0];
    const float* cosT = (const float*)d_in[1];
    const float* sinT = (const float*)d_in[2];
    const float* WAq  = (const float*)d_in[3];
    const float* WAk  = (const float*)d_in[4];
    const float* WAv  = (const float*)d_in[5];
    const float* WBq  = (const float*)d_in[6];
    const float* WBk  = (const float*)d_in[7];
    const float* WBv  = (const float*)d_in[8];
    const float* Wo   = (const float*)d_in[9];
    const float* qnw  = (const float*)d_in[10];
    const float* knw  = (const float*)d_in[11];
    const float* kcA  = (const float*)d_in[12];
    const float* kcB  = (const float*)d_in[13];
    const float* vcA  = (const float*)d_in[14];
    const float* vcB  = (const float*)d_in[15];
    const int*   kidx = (const int*)d_in[16];
    float* out = (float*)d_out;

    const size_t MROW = (size_t)B_ * S_;   // 4096
    char* w = (char*)d_ws;
    auto alloc = [&](size_t bytes) { char* r = w; w += (bytes + 255) & ~(size_t)255; return r; };

    unsigned short* hsbf = (unsigned short*)alloc(MROW * HID_ * 2);
    unsigned short* Wt   = (unsigned short*)alloc((size_t)NPACK * HID_ * 2);
    unsigned short* Wto  = (unsigned short*)alloc((size_t)HID_ * HID_ * 2);
    float* Cp  = (float*)alloc(MROW * NPACK * 4);
    float* eKA = (float*)alloc(MROW * 16 * 4);
    float* eKB = (float*)alloc(MROW * 256 * 4);
    float* eVA = (float*)alloc(MROW * 16 * 4);
    float* eVB = (float*)alloc(MROW * 256 * 4);
    unsigned short* Qbf = (unsigned short*)alloc((size_t)B_ * NH_  * S_ * D_ * 2);
    unsigned short* Kbf = (unsigned short*)alloc((size_t)B_ * NKV_ * S_ * D_ * 2);
    unsigned short* Vbf = (unsigned short*)alloc((size_t)B_ * NKV_ * S_ * D_ * 2);
    unsigned short* Vtb = (unsigned short*)alloc((size_t)B_ * NKV_ * S_ * D_ * 2);
    unsigned short* aObf = (unsigned short*)alloc(MROW * (NH_ * D_) * 2);

    const int M = (int)MROW;

    cvt_f32_bf16<<<(M * HID_ / 4 + 255) / 256, 256, 0, stream>>>(hs, hsbf, M * HID_ / 4);
    pack_weights<<<dim3(64, 64, 7), 256, 0, stream>>>(WAq, WAk, WAv, WBq, WBk, WBv, Wo, Wt, Wto);

    gemm_bf16<<<dim3(NPACK / 128, M / 128), 256, 0, stream>>>(hsbf, Wt, Cp, M, NPACK, HID_);

    norm_rope_all<<<dim3(M * QR_, 2), 64, 0, stream>>>(Cp, qnw, knw, cosT, sinT);

    {
        const int NA = B_ * S_ * 16 / 4, NB = B_ * S_ * 256 / 4;
        const int total = 2 * NA + 2 * NB;
        copy_caches<<<(total + 255) / 256, 256, 0, stream>>>(
            (const float4*)kcA, (const float4*)kcB, (const float4*)vcA, (const float4*)vcB,
            (float4*)eKA, (float4*)eKB, (float4*)eVA, (float4*)eVB);
    }
    scatter_kernel<<<M, 256, 0, stream>>>(Cp, kidx, eKA, eKB, eVA, eVB);

    assemble_kernel<<<M, 256, 0, stream>>>(Cp, eKA, eKB, eVA, eVB, Qbf, Kbf, Vbf);
    transpose_v<<<dim3(S_ / 64, 1, B_ * NKV_), 256, 0, stream>>>(Vbf, Vtb);

    attn_mfma<<<dim3(32, 32, 1), 256, 0, stream>>>(Qbf, Kbf, Vtb, aObf);

    gemm_bf16<<<dim3(HID_ / 128, M / 128), 256, 0, stream>>>(aObf, Wto, out, M, HID_, HID_);
}